// Round 2
// baseline (245.396 us; speedup 1.0000x reference)
//
#include <hip/hip_runtime.h>

typedef __bf16 bf16x8 __attribute__((ext_vector_type(8)));
typedef float f32x4 __attribute__((ext_vector_type(4)));
typedef unsigned short u16;
typedef unsigned int u32;

__device__ __forceinline__ float bf2f(u16 x){ u32 u = ((u32)x)<<16; return __builtin_bit_cast(float,u); }
__device__ __forceinline__ u16 f2bf(float f){ u32 u = __builtin_bit_cast(u32,f); u = (u + 0x7fffu + ((u>>16)&1u)) >> 16; return (u16)u; }

__device__ __forceinline__ void glds16(const u16* g, u16* l){
  __builtin_amdgcn_global_load_lds((const __attribute__((address_space(1))) u32*)g,
                                   (__attribute__((address_space(3))) u32*)l, 16, 0, 0);
}

static constexpr float L2E = 1.4426950408889634f;

// ---------------- f32 -> bf16 bulk convert (4 elems/thread) ----------------
__global__ void k_cvt(const float* __restrict__ s, u16* __restrict__ d, int n4){
  int i = blockIdx.x*256 + threadIdx.x;
  if (i >= n4) return;
  float4 v = reinterpret_cast<const float4*>(s)[i];
  ushort4 o = make_ushort4(f2bf(v.x), f2bf(v.y), f2bf(v.z), f2bf(v.w));
  reinterpret_cast<ushort4*>(d)[i] = o;
}

// ------- rel_table transpose + pre-scale by log2(e):  relT[h][i] -----------
__global__ void k_rel(const float* __restrict__ rt, float* __restrict__ o){
  int i = blockIdx.x*256 + threadIdx.x;
  int h = blockIdx.y;
  if (i < 3969) o[h*3969+i] = rt[i*8+h] * L2E;
}

// ------- depthwise 15-tap conv along token axis on pre-scaled Q ------------
__device__ __forceinline__ void acc8(float* acc, uint4 v, float w){
  acc[0]=fmaf(w, bf2f((u16)(v.x)),     acc[0]); acc[1]=fmaf(w, bf2f((u16)(v.x>>16)), acc[1]);
  acc[2]=fmaf(w, bf2f((u16)(v.y)),     acc[2]); acc[3]=fmaf(w, bf2f((u16)(v.y>>16)), acc[3]);
  acc[4]=fmaf(w, bf2f((u16)(v.z)),     acc[4]); acc[5]=fmaf(w, bf2f((u16)(v.z>>16)), acc[5]);
  acc[6]=fmaf(w, bf2f((u16)(v.w)),     acc[6]); acc[7]=fmaf(w, bf2f((u16)(v.w>>16)), acc[7]);
}
__global__ void k_qconv(const u16* __restrict__ q, u16* __restrict__ qp, const float* __restrict__ pw){
  int idx = blockIdx.x*256 + threadIdx.x;      // 524288 = 64bh * 1024n * 8 dchunks
  int dc = idx&7, n = (idx>>3)&1023, bh = idx>>13, h = bh&7;
  const u16* base = q + (long)bh*65536 + dc*8;
  float wgt[15];
  #pragma unroll
  for (int t=0;t<15;t++) wgt[t] = pw[h*15+t];
  float acc[8];
  {
    uint4 cv = *reinterpret_cast<const uint4*>(base + n*64);
    acc[0]=bf2f((u16)cv.x); acc[1]=bf2f((u16)(cv.x>>16));
    acc[2]=bf2f((u16)cv.y); acc[3]=bf2f((u16)(cv.y>>16));
    acc[4]=bf2f((u16)cv.z); acc[5]=bf2f((u16)(cv.z>>16));
    acc[6]=bf2f((u16)cv.w); acc[7]=bf2f((u16)(cv.w>>16));
  }
  #pragma unroll
  for (int t=0;t<15;t++){
    int nn = n - 7 + t;
    if (nn >= 0 && nn < 1024){
      uint4 v = *reinterpret_cast<const uint4*>(base + nn*64);
      acc8(acc, v, wgt[t]);
    }
  }
  u16* out = qp + (long)bh*65536 + n*64 + dc*8;
  *reinterpret_cast<ushort4*>(out)   = make_ushort4(f2bf(acc[0]),f2bf(acc[1]),f2bf(acc[2]),f2bf(acc[3]));
  *reinterpret_cast<ushort4*>(out+4) = make_ushort4(f2bf(acc[4]),f2bf(acc[5]),f2bf(acc[6]),f2bf(acc[7]));
}

// ---------------- 128x128 tile bf16 MFMA GEMM, C = A * Bw^T + bias ---------
// Staging via global_load_lds width=16. MODE 0: qkv scatter. MODE 1: f32 out.
template<int MODE>
__global__ __launch_bounds__(256) void k_gemm(
  const u16* __restrict__ A, const u16* __restrict__ Bw, const float* __restrict__ bias,
  u16* __restrict__ qo, u16* __restrict__ ko, u16* __restrict__ vo, float* __restrict__ co)
{
  constexpr int K = 512;
  __shared__ __align__(16) u16 lA[128*32];
  __shared__ __align__(16) u16 lB[128*32];
  const int T = threadIdx.x;
  const int w = T>>6, lane = T&63, g = lane>>4, cl = lane&15;
  const int i0 = blockIdx.y*128, j0 = blockIdx.x*128;
  const int wr = (w>>1)*64, wc = (w&1)*64;
  const int sr = T>>2, sk = 8*(T&3);
  f32x4 acc[4][4];
  #pragma unroll
  for (int a=0;a<4;a++)
    #pragma unroll
    for (int b=0;b<4;b++) acc[a][b] = (f32x4){0.f,0.f,0.f,0.f};

  for (int k0=0;k0<K;k0+=32){
    __syncthreads();
    glds16(A  + (long)(i0+sr)*K    + k0 + sk, lA + 8*T);
    glds16(A  + (long)(i0+64+sr)*K + k0 + sk, lA + 2048 + 8*T);
    glds16(Bw + (long)(j0+sr)*K    + k0 + sk, lB + 8*T);
    glds16(Bw + (long)(j0+64+sr)*K + k0 + sk, lB + 2048 + 8*T);
    __syncthreads();
    bf16x8 af[4], bfr[4];
    #pragma unroll
    for (int mf=0;mf<4;mf++) af[mf]  = *reinterpret_cast<const bf16x8*>(lA + (wr+16*mf+cl)*32 + 8*g);
    #pragma unroll
    for (int nf=0;nf<4;nf++) bfr[nf] = *reinterpret_cast<const bf16x8*>(lB + (wc+16*nf+cl)*32 + 8*g);
    #pragma unroll
    for (int mf=0;mf<4;mf++)
      #pragma unroll
      for (int nf=0;nf<4;nf++)
        acc[mf][nf] = __builtin_amdgcn_mfma_f32_16x16x32_bf16(af[mf], bfr[nf], acc[mf][nf], 0,0,0);
  }

  #pragma unroll
  for (int mf=0;mf<4;mf++){
    #pragma unroll
    for (int nf=0;nf<4;nf++){
      const int col = j0 + wc + 16*nf + cl;
      const float bb = bias[col];
      const int row0 = i0 + wr + 16*mf + 4*g;
      if (MODE==0){
        const int part = col>>9, h=(col>>6)&7, dd=col&63;
        const int b = row0>>10, n0 = row0&1023, bh = b*8+h;
        if (part==2){
          ushort4 pk = make_ushort4(f2bf(acc[mf][nf][0]+bb), f2bf(acc[mf][nf][1]+bb),
                                    f2bf(acc[mf][nf][2]+bb), f2bf(acc[mf][nf][3]+bb));
          *reinterpret_cast<ushort4*>(vo + ((long)bh*64+dd)*1024 + n0) = pk;
        } else {
          #pragma unroll
          for (int e=0;e<4;e++){
            float v = acc[mf][nf][e] + bb;
            if (part==0) qo[((long)bh*1024+n0+e)*64+dd] = f2bf(v*0.125f);
            else         ko[((long)bh*1024+n0+e)*64+dd] = f2bf(v);
          }
        }
      } else {
        #pragma unroll
        for (int e=0;e<4;e++)
          co[(long)(row0+e)*512 + col] = acc[mf][nf][e] + bb;
      }
    }
  }
}

// ---------------- fused window attention, v2 -------------------------------
// Swapped QK^T (P in registers), no-max softmax, deferred l-reduction,
// XCD-aware block mapping. 1024 blocks x 4 waves, 16 q-rows/wave.
__global__ __launch_bounds__(256,4) void k_attn(
  const u16* __restrict__ Qp, const u16* __restrict__ Kb, const u16* __restrict__ VT,
  const float* __restrict__ relT, u16* __restrict__ Ao)
{
  __shared__ float rel[3969];
  const int bid = blockIdx.x;
  const int xcd = bid&7, slot = bid>>3;
  const int bh = xcd*8 + (slot>>4), rb = slot&15;   // all 16 rowblocks of a bh on one XCD
  const int b = bh>>3, h = bh&7;
  const int T = threadIdx.x, w=T>>6, lane=T&63, g=lane>>4, cl=lane&15;
  for (int i=T;i<3969;i+=256) rel[i] = relT[h*3969+i];
  const int rowbase = rb*64 + w*16;
  const int qrow = rowbase + cl;                    // this lane's q-row (P side)
  const u16* Qr = Qp + ((long)bh*1024 + qrow)*64;
  const bf16x8 qf0 = *reinterpret_cast<const bf16x8*>(Qr + 8*g);
  const bf16x8 qf1 = *reinterpret_cast<const bf16x8*>(Qr + 32 + 8*g);
  const int rt = (qrow>>5)*63 + (qrow&31) + 1984;
  const u16* Kbh = Kb + (long)bh*65536;
  const u16* Vbh = VT + (long)bh*65536;
  float lsum = 0.f;
  f32x4 oacc[4];
  #pragma unroll
  for (int c=0;c<4;c++) oacc[c] = (f32x4){0.f,0.f,0.f,0.f};
  __syncthreads();

  for (int m0=0;m0<1024;m0+=64){
    // K fragments (A-operand): lane (g,cl) = K[m0+16c+cl][8g..], [32+8g..]
    bf16x8 kf[4][2];
    #pragma unroll
    for (int c=0;c<4;c++){
      const u16* Kr = Kbh + (m0+16*c+cl)*64;
      kf[c][0] = *reinterpret_cast<const bf16x8*>(Kr + 8*g);
      kf[c][1] = *reinterpret_cast<const bf16x8*>(Kr + 32 + 8*g);
    }
    // V fragments, sigma-pattern: j<4 -> k=32ks+4g+j ; j>=4 -> k=32ks+16+4g+(j-4)
    ushort4 va[2][4], vb[2][4];
    #pragma unroll
    for (int ks=0;ks<2;ks++)
      #pragma unroll
      for (int c2=0;c2<4;c2++){
        const u16* Vr = Vbh + (16*c2+cl)*1024 + m0 + 32*ks + 4*g;
        va[ks][c2] = *reinterpret_cast<const ushort4*>(Vr);
        vb[ks][c2] = *reinterpret_cast<const ushort4*>(Vr + 16);
      }
    // S^T = K . Q^T : sacc[c][e] = S[q=rowbase+cl][k=m0+16c+4g+e]
    f32x4 sacc[4];
    #pragma unroll
    for (int c=0;c<4;c++){
      sacc[c] = (f32x4){0.f,0.f,0.f,0.f};
      sacc[c] = __builtin_amdgcn_mfma_f32_16x16x32_bf16(kf[c][0], qf0, sacc[c],0,0,0);
      sacc[c] = __builtin_amdgcn_mfma_f32_16x16x32_bf16(kf[c][1], qf1, sacc[c],0,0,0);
    }
    // p = exp(s + bias), no max subtraction (scores bounded), lsum deferred
    float p[4][4];
    #pragma unroll
    for (int c=0;c<4;c++){
      const int kk = m0 + 16*c + 4*g;
      const int ridx = rt - ((kk>>5)*63 + (kk&31));
      #pragma unroll
      for (int e=0;e<4;e++)
        p[c][e] = exp2f(fmaf(sacc[c][e], L2E, rel[ridx - e]));
    }
    #pragma unroll
    for (int c=0;c<4;c++) lsum += (p[c][0]+p[c][1]) + (p[c][2]+p[c][3]);
    // pack P to bf16 A-fragments matching sigma
    bf16x8 pa0, pa1;
    #pragma unroll
    for (int e=0;e<4;e++){
      pa0[e]   = (__bf16)p[0][e];  pa0[4+e] = (__bf16)p[1][e];
      pa1[e]   = (__bf16)p[2][e];  pa1[4+e] = (__bf16)p[3][e];
    }
    #pragma unroll
    for (int c2=0;c2<4;c2++){
      union { bf16x8 v; ushort4 q[2]; } vf0, vf1;
      vf0.q[0]=va[0][c2]; vf0.q[1]=vb[0][c2];
      vf1.q[0]=va[1][c2]; vf1.q[1]=vb[1][c2];
      oacc[c2] = __builtin_amdgcn_mfma_f32_16x16x32_bf16(pa0, vf0.v, oacc[c2],0,0,0);
      oacc[c2] = __builtin_amdgcn_mfma_f32_16x16x32_bf16(pa1, vf1.v, oacc[c2],0,0,0);
    }
  }
  // deferred l reduction across the 4 g-groups, then broadcast to O-rows
  lsum += __shfl_xor(lsum, 16, 64);
  lsum += __shfl_xor(lsum, 32, 64);
  #pragma unroll
  for (int e=0;e<4;e++){
    float inv = 1.0f/__shfl(lsum, 4*g+e, 64);
    const long orow = (long)b*1024 + rowbase + 4*g + e;
    #pragma unroll
    for (int c2=0;c2<4;c2++)
      Ao[orow*512 + h*64 + 16*c2 + cl] = f2bf(oacc[c2][e]*inv);
  }
}

extern "C" void kernel_launch(void* const* d_in, const int* in_sizes, int n_in,
                              void* d_out, int out_size, void* d_ws, size_t ws_size,
                              hipStream_t stream)
{
  const float* x         = (const float*)d_in[0];
  const float* w_qkv     = (const float*)d_in[1];
  const float* b_qkv     = (const float*)d_in[2];
  const float* w_proj    = (const float*)d_in[3];
  const float* b_proj    = (const float*)d_in[4];
  const float* rel_table = (const float*)d_in[5];
  const float* pe_w      = (const float*)d_in[6];
  (void)in_sizes; (void)n_in; (void)out_size; (void)ws_size;

  u16* ws    = (u16*)d_ws;
  u16* x_bf  = ws;                  // 8192*512 (freed after gemm<0>; reused for relT)
  u16* wq_bf = x_bf  + 4194304;     // 1536*512
  u16* wp_bf = wq_bf + 786432;      // 512*512
  u16* q_bf  = wp_bf + 262144;      // [B,H,N,64] pre-scaled
  u16* k_bf  = q_bf  + 4194304;     // [B,H,N,64]
  u16* vt_bf = k_bf  + 4194304;     // [B,H,64,N]
  u16* qp_bf = vt_bf + 4194304;     // Q' = q~ + conv(q~)
  u16* ao_bf = qp_bf + 4194304;     // attention out [B,N,C]
  float* relT = (float*)x_bf;       // [H][3969], written after gemm<0> consumed x_bf

  k_cvt<<<4096,256,0,stream>>>(x, x_bf, 1048576);
  k_cvt<<<768,256,0,stream>>>(w_qkv, wq_bf, 196608);
  k_cvt<<<256,256,0,stream>>>(w_proj, wp_bf, 65536);
  k_gemm<0><<<dim3(12,64),256,0,stream>>>(x_bf, wq_bf, b_qkv, q_bf, k_bf, vt_bf, nullptr);
  k_rel<<<dim3(16,8),256,0,stream>>>(rel_table, relT);
  k_qconv<<<2048,256,0,stream>>>(q_bf, qp_bf, pe_w);
  k_attn<<<1024,256,0,stream>>>(qp_bf, k_bf, vt_bf, relT, ao_bf);
  k_gemm<1><<<dim3(4,64),256,0,stream>>>(ao_bf, wp_bf, b_proj, nullptr, nullptr, nullptr, (float*)d_out);
}

// Round 3
// 126.389 us; speedup vs baseline: 1.9416x; 1.9416x over previous
//
#include <hip/hip_runtime.h>

typedef __bf16 bf16x8 __attribute__((ext_vector_type(8)));
typedef float f32x4 __attribute__((ext_vector_type(4)));
typedef unsigned short u16;
typedef unsigned int u32;
typedef unsigned long long u64;

__device__ __forceinline__ float bf2f(u16 x){ u32 u = ((u32)x)<<16; return __builtin_bit_cast(float,u); }
__device__ __forceinline__ u16 f2bf(float f){ u32 u = __builtin_bit_cast(u32,f); u = (u + 0x7fffu + ((u>>16)&1u)) >> 16; return (u16)u; }

__device__ __forceinline__ void glds16(const u16* g, u16* l){
  __builtin_amdgcn_global_load_lds((const __attribute__((address_space(1))) u32*)g,
                                   (__attribute__((address_space(3))) u32*)l, 16, 0, 0);
}

static constexpr float L2E = 1.4426950408889634f;

// ---------------- f32 -> bf16 bulk convert (4 elems/thread) ----------------
__global__ void k_cvt(const float* __restrict__ s, u16* __restrict__ d, int n4){
  int i = blockIdx.x*256 + threadIdx.x;
  if (i >= n4) return;
  float4 v = reinterpret_cast<const float4*>(s)[i];
  ushort4 o = make_ushort4(f2bf(v.x), f2bf(v.y), f2bf(v.z), f2bf(v.w));
  reinterpret_cast<ushort4*>(d)[i] = o;
}

// ------- rel_table transpose + pre-scale by log2(e), bf16 out --------------
__global__ void k_rel(const float* __restrict__ rt, u16* __restrict__ o){
  int i = blockIdx.x*256 + threadIdx.x;
  int h = blockIdx.y;
  if (i < 3969) o[h*3969+i] = f2bf(rt[i*8+h] * L2E);
}

// ------- depthwise 15-tap conv along token axis on pre-scaled Q ------------
__device__ __forceinline__ void acc8(float* acc, uint4 v, float w){
  acc[0]=fmaf(w, bf2f((u16)(v.x)),     acc[0]); acc[1]=fmaf(w, bf2f((u16)(v.x>>16)), acc[1]);
  acc[2]=fmaf(w, bf2f((u16)(v.y)),     acc[2]); acc[3]=fmaf(w, bf2f((u16)(v.y>>16)), acc[3]);
  acc[4]=fmaf(w, bf2f((u16)(v.z)),     acc[4]); acc[5]=fmaf(w, bf2f((u16)(v.z>>16)), acc[5]);
  acc[6]=fmaf(w, bf2f((u16)(v.w)),     acc[6]); acc[7]=fmaf(w, bf2f((u16)(v.w>>16)), acc[7]);
}
__global__ void k_qconv(const u16* __restrict__ q, u16* __restrict__ qp, const float* __restrict__ pw){
  int idx = blockIdx.x*256 + threadIdx.x;      // 524288 = 64bh * 1024n * 8 dchunks
  int dc = idx&7, n = (idx>>3)&1023, bh = idx>>13, h = bh&7;
  const u16* base = q + (long)bh*65536 + dc*8;
  float wgt[15];
  #pragma unroll
  for (int t=0;t<15;t++) wgt[t] = pw[h*15+t];
  float acc[8];
  {
    uint4 cv = *reinterpret_cast<const uint4*>(base + n*64);
    acc[0]=bf2f((u16)cv.x); acc[1]=bf2f((u16)(cv.x>>16));
    acc[2]=bf2f((u16)cv.y); acc[3]=bf2f((u16)(cv.y>>16));
    acc[4]=bf2f((u16)cv.z); acc[5]=bf2f((u16)(cv.z>>16));
    acc[6]=bf2f((u16)cv.w); acc[7]=bf2f((u16)(cv.w>>16));
  }
  #pragma unroll
  for (int t=0;t<15;t++){
    int nn = n - 7 + t;
    if (nn >= 0 && nn < 1024){
      uint4 v = *reinterpret_cast<const uint4*>(base + nn*64);
      acc8(acc, v, wgt[t]);
    }
  }
  u16* out = qp + (long)bh*65536 + n*64 + dc*8;
  *reinterpret_cast<ushort4*>(out)   = make_ushort4(f2bf(acc[0]),f2bf(acc[1]),f2bf(acc[2]),f2bf(acc[3]));
  *reinterpret_cast<ushort4*>(out+4) = make_ushort4(f2bf(acc[4]),f2bf(acc[5]),f2bf(acc[6]),f2bf(acc[7]));
}

// ---------------- 128x128 tile bf16 MFMA GEMM, C = A * Bw^T + bias ---------
template<int MODE>
__global__ __launch_bounds__(256) void k_gemm(
  const u16* __restrict__ A, const u16* __restrict__ Bw, const float* __restrict__ bias,
  u16* __restrict__ qo, u16* __restrict__ ko, u16* __restrict__ vo, float* __restrict__ co)
{
  constexpr int K = 512;
  __shared__ __align__(16) u16 lA[128*32];
  __shared__ __align__(16) u16 lB[128*32];
  const int T = threadIdx.x;
  const int w = T>>6, lane = T&63, g = lane>>4, cl = lane&15;
  const int i0 = blockIdx.y*128, j0 = blockIdx.x*128;
  const int wr = (w>>1)*64, wc = (w&1)*64;
  const int sr = T>>2, sk = 8*(T&3);
  f32x4 acc[4][4];
  #pragma unroll
  for (int a=0;a<4;a++)
    #pragma unroll
    for (int b=0;b<4;b++) acc[a][b] = (f32x4){0.f,0.f,0.f,0.f};

  for (int k0=0;k0<K;k0+=32){
    __syncthreads();
    glds16(A  + (long)(i0+sr)*K    + k0 + sk, lA + 8*T);
    glds16(A  + (long)(i0+64+sr)*K + k0 + sk, lA + 2048 + 8*T);
    glds16(Bw + (long)(j0+sr)*K    + k0 + sk, lB + 8*T);
    glds16(Bw + (long)(j0+64+sr)*K + k0 + sk, lB + 2048 + 8*T);
    __syncthreads();
    bf16x8 af[4], bfr[4];
    #pragma unroll
    for (int mf=0;mf<4;mf++) af[mf]  = *reinterpret_cast<const bf16x8*>(lA + (wr+16*mf+cl)*32 + 8*g);
    #pragma unroll
    for (int nf=0;nf<4;nf++) bfr[nf] = *reinterpret_cast<const bf16x8*>(lB + (wc+16*nf+cl)*32 + 8*g);
    #pragma unroll
    for (int mf=0;mf<4;mf++)
      #pragma unroll
      for (int nf=0;nf<4;nf++)
        acc[mf][nf] = __builtin_amdgcn_mfma_f32_16x16x32_bf16(af[mf], bfr[nf], acc[mf][nf], 0,0,0);
  }

  #pragma unroll
  for (int mf=0;mf<4;mf++){
    #pragma unroll
    for (int nf=0;nf<4;nf++){
      const int col = j0 + wc + 16*nf + cl;
      const float bb = bias[col];
      const int row0 = i0 + wr + 16*mf + 4*g;
      if (MODE==0){
        const int part = col>>9, h=(col>>6)&7, dd=col&63;
        const int b = row0>>10, n0 = row0&1023, bh = b*8+h;
        if (part==2){
          ushort4 pk = make_ushort4(f2bf(acc[mf][nf][0]+bb), f2bf(acc[mf][nf][1]+bb),
                                    f2bf(acc[mf][nf][2]+bb), f2bf(acc[mf][nf][3]+bb));
          *reinterpret_cast<ushort4*>(vo + ((long)bh*64+dd)*1024 + n0) = pk;
        } else {
          #pragma unroll
          for (int e=0;e<4;e++){
            float v = acc[mf][nf][e] + bb;
            if (part==0) qo[((long)bh*1024+n0+e)*64+dd] = f2bf(v*0.125f);
            else         ko[((long)bh*1024+n0+e)*64+dd] = f2bf(v);
          }
        }
      } else {
        #pragma unroll
        for (int e=0;e<4;e++)
          co[(long)(row0+e)*512 + col] = acc[mf][nf][e] + bb;
      }
    }
  }
}

// ---------------- fused window attention, v3 -------------------------------
// LDS-staged K/V (global_load_lds w16, XOR-swizzled via pre-swizzled source),
// double-buffered 2-phase pipeline, P in registers, no-max softmax.
// 1024 blocks x 4 waves; 16 q-rows/wave; KV tiles of 64.
__global__ __launch_bounds__(256,4) void k_attn(
  const u16* __restrict__ Qp, const u16* __restrict__ Kb, const u16* __restrict__ VT,
  const u16* __restrict__ relT, u16* __restrict__ Ao)
{
  __shared__ u16 rel[3976];
  __shared__ __align__(16) u16 kls[2][4096];
  __shared__ __align__(16) u16 vls[2][4096];
  const int bid = blockIdx.x;
  const int xcd = bid&7, slot = bid>>3;
  const int bh = xcd*8 + (slot>>4), rb = slot&15;   // all 16 rowblocks of a bh on one XCD
  const int b = bh>>3, h = bh&7;
  const int T = threadIdx.x, w=T>>6, lane=T&63, g=lane>>4, cl=lane&15;
  for (int i=T;i<3969;i+=256) rel[i] = relT[h*3969+i];
  const int rowbase = rb*64 + w*16;
  const int qrow = rowbase + cl;
  const u16* Qr = Qp + ((long)bh*1024 + qrow)*64;
  const bf16x8 qf0 = *reinterpret_cast<const bf16x8*>(Qr + 8*g);
  const bf16x8 qf1 = *reinterpret_cast<const bf16x8*>(Qr + 32 + 8*g);
  const int rt = (qrow>>5)*63 + (qrow&31) + 1984;
  const u16* Kbh = Kb + (long)bh*65536;
  const u16* Vbh = VT + (long)bh*65536;
  float lsum = 0.f;
  f32x4 oacc[4];
  #pragma unroll
  for (int c=0;c<4;c++) oacc[c] = (f32x4){0.f,0.f,0.f,0.f};

  // stage tile 0 (pre-swizzled source -> linear LDS dest; read applies XOR)
  #pragma unroll
  for (int s=0;s<2;s++){
    int idx = s*256 + T, row = idx>>3, u = idx&7, sw = (u ^ (row&7))<<3;
    glds16(Kbh + row*64 + sw,           kls[0] + idx*8);
    glds16(Vbh + (long)row*1024 + sw,   vls[0] + idx*8);
  }
  __syncthreads();

  for (int t=0;t<16;t++){
    const int m0 = t<<6, cur = t&1;
    if (t<15){
      const int m1 = m0+64, nxt = cur^1;
      #pragma unroll
      for (int s=0;s<2;s++){
        int idx = s*256 + T, row = idx>>3, u = idx&7, sw = (u ^ (row&7))<<3;
        glds16(Kbh + (m1+row)*64 + sw,        kls[nxt] + idx*8);
        glds16(Vbh + (long)row*1024 + m1 + sw, vls[nxt] + idx*8);
      }
    }
    const char* kb = (const char*)kls[cur];
    const char* vb = (const char*)vls[cur];
    // QK^T (swapped): sacc[c][e] = S[q=rowbase+cl][k=m0+16c+4g+e]
    f32x4 sacc[4];
    #pragma unroll
    for (int c=0;c<4;c++){
      const int r = 16*c + cl, rs = (r&7);
      const char* kr = kb + r*128;
      bf16x8 kf0 = *reinterpret_cast<const bf16x8*>(kr + ((g    ^rs)<<4));
      bf16x8 kf1 = *reinterpret_cast<const bf16x8*>(kr + (((4+g)^rs)<<4));
      sacc[c] = (f32x4){0.f,0.f,0.f,0.f};
      sacc[c] = __builtin_amdgcn_mfma_f32_16x16x32_bf16(kf0, qf0, sacc[c],0,0,0);
      sacc[c] = __builtin_amdgcn_mfma_f32_16x16x32_bf16(kf1, qf1, sacc[c],0,0,0);
    }
    // p = exp2(s*log2e + relL2E), no max subtraction; lsum deferred
    float p[4][4];
    #pragma unroll
    for (int c=0;c<4;c++){
      const int kk = m0 + 16*c + 4*g;
      const int ridx = rt - ((kk>>5)*63 + (kk&31));
      #pragma unroll
      for (int e=0;e<4;e++)
        p[c][e] = exp2f(fmaf(sacc[c][e], L2E, bf2f(rel[ridx - e])));
    }
    #pragma unroll
    for (int c=0;c<4;c++) lsum += (p[c][0]+p[c][1]) + (p[c][2]+p[c][3]);
    // pack P to bf16 A-fragments (sigma: j<4 -> k=4g+j ; j>=4 -> k=16+4g+(j-4))
    bf16x8 pa0, pa1;
    #pragma unroll
    for (int e=0;e<4;e++){
      pa0[e]   = (__bf16)p[0][e];  pa0[4+e] = (__bf16)p[1][e];
      pa1[e]   = (__bf16)p[2][e];  pa1[4+e] = (__bf16)p[3][e];
    }
    // PV: V fragments from swizzled LDS, same sigma on B side
    #pragma unroll
    for (int ks=0;ks<2;ks++){
      const bf16x8 pa = ks ? pa1 : pa0;
      #pragma unroll
      for (int c2=0;c2<4;c2++){
        const int dd = 16*c2 + cl, dsw = (dd&7);
        const char* vr = vb + dd*128;
        const int ua = 64*ks + 8*g;        // byte offset of k-slots j<4
        union { bf16x8 v; u64 q[2]; } vf;
        vf.q[0] = *reinterpret_cast<const u64*>(vr + ((((ua   )>>4)^dsw)<<4) + (ua&15));
        vf.q[1] = *reinterpret_cast<const u64*>(vr + ((((ua+32)>>4)^dsw)<<4) + (ua&15));
        oacc[c2] = __builtin_amdgcn_mfma_f32_16x16x32_bf16(pa, vf.v, oacc[c2],0,0,0);
      }
    }
    __syncthreads();
  }
  // deferred l reduction across the 4 g-groups, then broadcast to O-rows
  lsum += __shfl_xor(lsum, 16, 64);
  lsum += __shfl_xor(lsum, 32, 64);
  #pragma unroll
  for (int e=0;e<4;e++){
    float inv = 1.0f/__shfl(lsum, 4*g+e, 64);
    const long orow = (long)b*1024 + rowbase + 4*g + e;
    #pragma unroll
    for (int c2=0;c2<4;c2++)
      Ao[orow*512 + h*64 + 16*c2 + cl] = f2bf(oacc[c2][e]*inv);
  }
}

extern "C" void kernel_launch(void* const* d_in, const int* in_sizes, int n_in,
                              void* d_out, int out_size, void* d_ws, size_t ws_size,
                              hipStream_t stream)
{
  const float* x         = (const float*)d_in[0];
  const float* w_qkv     = (const float*)d_in[1];
  const float* b_qkv     = (const float*)d_in[2];
  const float* w_proj    = (const float*)d_in[3];
  const float* b_proj    = (const float*)d_in[4];
  const float* rel_table = (const float*)d_in[5];
  const float* pe_w      = (const float*)d_in[6];
  (void)in_sizes; (void)n_in; (void)out_size; (void)ws_size;

  u16* ws    = (u16*)d_ws;
  u16* x_bf  = ws;                  // 8192*512 (reused for relT after gemm<0>)
  u16* wq_bf = x_bf  + 4194304;     // 1536*512
  u16* wp_bf = wq_bf + 786432;      // 512*512
  u16* q_bf  = wp_bf + 262144;      // [B,H,N,64] pre-scaled
  u16* k_bf  = q_bf  + 4194304;     // [B,H,N,64]
  u16* vt_bf = k_bf  + 4194304;     // [B,H,64,N]
  u16* qp_bf = vt_bf + 4194304;     // Q' = q~ + conv(q~)
  u16* ao_bf = qp_bf + 4194304;     // attention out [B,N,C]
  u16* relT  = x_bf;                // [H][3969] bf16, written after gemm<0>

  k_cvt<<<4096,256,0,stream>>>(x, x_bf, 1048576);
  k_cvt<<<768,256,0,stream>>>(w_qkv, wq_bf, 196608);
  k_cvt<<<256,256,0,stream>>>(w_proj, wp_bf, 65536);
  k_gemm<0><<<dim3(12,64),256,0,stream>>>(x_bf, wq_bf, b_qkv, q_bf, k_bf, vt_bf, nullptr);
  k_rel<<<dim3(16,8),256,0,stream>>>(rel_table, relT);
  k_qconv<<<2048,256,0,stream>>>(q_bf, qp_bf, pe_w);
  k_attn<<<1024,256,0,stream>>>(qp_bf, k_bf, vt_bf, relT, ao_bf);
  k_gemm<1><<<dim3(4,64),256,0,stream>>>(ao_bf, wp_bf, b_proj, nullptr, nullptr, nullptr, (float*)d_out);
}

// Round 4
// 120.218 us; speedup vs baseline: 2.0413x; 1.0513x over previous
//
#include <hip/hip_runtime.h>

typedef __bf16 bf16x8 __attribute__((ext_vector_type(8)));
typedef float f32x4 __attribute__((ext_vector_type(4)));
typedef unsigned short u16;
typedef unsigned int u32;
typedef unsigned long long u64;

__device__ __forceinline__ float bf2f(u16 x){ u32 u = ((u32)x)<<16; return __builtin_bit_cast(float,u); }
__device__ __forceinline__ u16 f2bf(float f){ u32 u = __builtin_bit_cast(u32,f); u = (u + 0x7fffu + ((u>>16)&1u)) >> 16; return (u16)u; }

__device__ __forceinline__ void glds16(const u16* g, u16* l){
  __builtin_amdgcn_global_load_lds((const __attribute__((address_space(1))) u32*)g,
                                   (__attribute__((address_space(3))) u32*)l, 16, 0, 0);
}

static constexpr float L2E = 1.4426950408889634f;
static constexpr float QSC = 0.125f * 1.4426950408889634f;  // SCALE * log2(e)

// ---------------- f32 -> bf16 bulk convert (4 elems/thread) ----------------
__global__ void k_cvt(const float* __restrict__ s, u16* __restrict__ d, int n4){
  int i = blockIdx.x*256 + threadIdx.x;
  if (i >= n4) return;
  float4 v = reinterpret_cast<const float4*>(s)[i];
  ushort4 o = make_ushort4(f2bf(v.x), f2bf(v.y), f2bf(v.z), f2bf(v.w));
  reinterpret_cast<ushort4*>(d)[i] = o;
}

// ------- rel_table transpose + pre-scale by log2(e), bf16 out --------------
__global__ void k_rel(const float* __restrict__ rt, u16* __restrict__ o){
  int i = blockIdx.x*256 + threadIdx.x;
  int h = blockIdx.y;
  if (i < 3969) o[h*3969+i] = f2bf(rt[i*8+h] * L2E);
}

// ------- depthwise 15-tap conv along token axis on pre-scaled Q ------------
__device__ __forceinline__ void acc8(float* acc, uint4 v, float w){
  acc[0]=fmaf(w, bf2f((u16)(v.x)),     acc[0]); acc[1]=fmaf(w, bf2f((u16)(v.x>>16)), acc[1]);
  acc[2]=fmaf(w, bf2f((u16)(v.y)),     acc[2]); acc[3]=fmaf(w, bf2f((u16)(v.y>>16)), acc[3]);
  acc[4]=fmaf(w, bf2f((u16)(v.z)),     acc[4]); acc[5]=fmaf(w, bf2f((u16)(v.z>>16)), acc[5]);
  acc[6]=fmaf(w, bf2f((u16)(v.w)),     acc[6]); acc[7]=fmaf(w, bf2f((u16)(v.w>>16)), acc[7]);
}
__global__ void k_qconv(const u16* __restrict__ q, u16* __restrict__ qp, const float* __restrict__ pw){
  int idx = blockIdx.x*256 + threadIdx.x;      // 524288 = 64bh * 1024n * 8 dchunks
  int dc = idx&7, n = (idx>>3)&1023, bh = idx>>13, h = bh&7;
  const u16* base = q + (long)bh*65536 + dc*8;
  float wgt[15];
  #pragma unroll
  for (int t=0;t<15;t++) wgt[t] = pw[h*15+t];
  float acc[8];
  {
    uint4 cv = *reinterpret_cast<const uint4*>(base + n*64);
    acc[0]=bf2f((u16)cv.x); acc[1]=bf2f((u16)(cv.x>>16));
    acc[2]=bf2f((u16)cv.y); acc[3]=bf2f((u16)(cv.y>>16));
    acc[4]=bf2f((u16)cv.z); acc[5]=bf2f((u16)(cv.z>>16));
    acc[6]=bf2f((u16)cv.w); acc[7]=bf2f((u16)(cv.w>>16));
  }
  #pragma unroll
  for (int t=0;t<15;t++){
    int nn = n - 7 + t;
    if (nn >= 0 && nn < 1024){
      uint4 v = *reinterpret_cast<const uint4*>(base + nn*64);
      acc8(acc, v, wgt[t]);
    }
  }
  u16* out = qp + (long)bh*65536 + n*64 + dc*8;
  *reinterpret_cast<ushort4*>(out)   = make_ushort4(f2bf(acc[0]),f2bf(acc[1]),f2bf(acc[2]),f2bf(acc[3]));
  *reinterpret_cast<ushort4*>(out+4) = make_ushort4(f2bf(acc[4]),f2bf(acc[5]),f2bf(acc[6]),f2bf(acc[7]));
}

// ---------------- 128x128 tile bf16 MFMA GEMM, C = A * Bw^T + bias ---------
// MODE 0: qkv scatter (Q pre-scaled by QSC; V^T stored sigma-permuted).
// MODE 1: f32 out.
template<int MODE>
__global__ __launch_bounds__(256) void k_gemm(
  const u16* __restrict__ A, const u16* __restrict__ Bw, const float* __restrict__ bias,
  u16* __restrict__ qo, u16* __restrict__ ko, u16* __restrict__ vo, float* __restrict__ co)
{
  constexpr int K = 512;
  __shared__ __align__(16) u16 lA[128*32];
  __shared__ __align__(16) u16 lB[128*32];
  const int T = threadIdx.x;
  const int w = T>>6, lane = T&63, g = lane>>4, cl = lane&15;
  const int i0 = blockIdx.y*128, j0 = blockIdx.x*128;
  const int wr = (w>>1)*64, wc = (w&1)*64;
  const int sr = T>>2, sk = 8*(T&3);
  f32x4 acc[4][4];
  #pragma unroll
  for (int a=0;a<4;a++)
    #pragma unroll
    for (int b=0;b<4;b++) acc[a][b] = (f32x4){0.f,0.f,0.f,0.f};

  for (int k0=0;k0<K;k0+=32){
    __syncthreads();
    glds16(A  + (long)(i0+sr)*K    + k0 + sk, lA + 8*T);
    glds16(A  + (long)(i0+64+sr)*K + k0 + sk, lA + 2048 + 8*T);
    glds16(Bw + (long)(j0+sr)*K    + k0 + sk, lB + 8*T);
    glds16(Bw + (long)(j0+64+sr)*K + k0 + sk, lB + 2048 + 8*T);
    __syncthreads();
    bf16x8 af[4], bfr[4];
    #pragma unroll
    for (int mf=0;mf<4;mf++) af[mf]  = *reinterpret_cast<const bf16x8*>(lA + (wr+16*mf+cl)*32 + 8*g);
    #pragma unroll
    for (int nf=0;nf<4;nf++) bfr[nf] = *reinterpret_cast<const bf16x8*>(lB + (wc+16*nf+cl)*32 + 8*g);
    #pragma unroll
    for (int mf=0;mf<4;mf++)
      #pragma unroll
      for (int nf=0;nf<4;nf++)
        acc[mf][nf] = __builtin_amdgcn_mfma_f32_16x16x32_bf16(af[mf], bfr[nf], acc[mf][nf], 0,0,0);
  }

  #pragma unroll
  for (int mf=0;mf<4;mf++){
    #pragma unroll
    for (int nf=0;nf<4;nf++){
      const int col = j0 + wc + 16*nf + cl;
      const float bb = bias[col];
      const int row0 = i0 + wr + 16*mf + 4*g;
      if (MODE==0){
        const int part = col>>9, h=(col>>6)&7, dd=col&63;
        const int b = row0>>10, n0 = row0&1023, bh = b*8+h;
        if (part==2){
          // V^T sigma-permuted within 32-token blocks:
          // token r=4G+j -> st = (G<4) ? 8G+j : 8(G-4)+4+j
          const int a32 = n0 & ~31, G = (n0>>2)&7;
          const int stb = ((G&3)<<3) | ((G>>2)<<2);
          ushort4 pk = make_ushort4(f2bf(acc[mf][nf][0]+bb), f2bf(acc[mf][nf][1]+bb),
                                    f2bf(acc[mf][nf][2]+bb), f2bf(acc[mf][nf][3]+bb));
          *reinterpret_cast<ushort4*>(vo + ((long)bh*64+dd)*1024 + a32 + stb) = pk;
        } else {
          #pragma unroll
          for (int e=0;e<4;e++){
            float v = acc[mf][nf][e] + bb;
            if (part==0) qo[((long)bh*1024+n0+e)*64+dd] = f2bf(v*QSC);
            else         ko[((long)bh*1024+n0+e)*64+dd] = f2bf(v);
          }
        }
      } else {
        #pragma unroll
        for (int e=0;e<4;e++)
          co[(long)(row0+e)*512 + col] = acc[mf][nf][e] + bb;
      }
    }
  }
}

// ---------------- fused window attention, v4 -------------------------------
// Swapped QK^T with bias-as-accumulator-init, raw v_exp_f32, single-b128
// V fragments (sigma-permuted layout), LDS dbuf K/V, setprio on MFMA.
__global__ __launch_bounds__(256,4) void k_attn(
  const u16* __restrict__ Qp, const u16* __restrict__ Kb, const u16* __restrict__ VT,
  const u16* __restrict__ relT, u16* __restrict__ Ao)
{
  __shared__ u16 rel[3976];
  __shared__ __align__(16) u16 kls[2][4096];
  __shared__ __align__(16) u16 vls[2][4096];
  const int bid = blockIdx.x;
  const int xcd = bid&7, slot = bid>>3;
  const int bh = xcd*8 + (slot>>4), rb = slot&15;   // all 16 rowblocks of a bh on one XCD
  const int b = bh>>3, h = bh&7;
  const int T = threadIdx.x, w=T>>6, lane=T&63, g=lane>>4, cl=lane&15;
  for (int i=T;i<3969;i+=256) rel[i] = relT[h*3969+i];
  const int rowbase = rb*64 + w*16;
  const int qrow = rowbase + cl;
  const u16* Qr = Qp + ((long)bh*1024 + qrow)*64;
  const bf16x8 qf0 = *reinterpret_cast<const bf16x8*>(Qr + 8*g);
  const bf16x8 qf1 = *reinterpret_cast<const bf16x8*>(Qr + 32 + 8*g);
  const int rt = (qrow>>5)*63 + (qrow&31) + 1984;
  const u16* Kbh = Kb + (long)bh*65536;
  const u16* Vbh = VT + (long)bh*65536;
  float lsum = 0.f;
  f32x4 oacc[4];
  #pragma unroll
  for (int c=0;c<4;c++) oacc[c] = (f32x4){0.f,0.f,0.f,0.f};

  // stage tile 0 (pre-swizzled source -> linear LDS dest; read applies XOR)
  #pragma unroll
  for (int s=0;s<2;s++){
    int idx = s*256 + T, row = idx>>3, u = idx&7, sw = (u ^ (row&7))<<3;
    glds16(Kbh + row*64 + sw,           kls[0] + idx*8);
    glds16(Vbh + (long)row*1024 + sw,   vls[0] + idx*8);
  }
  __syncthreads();

  for (int t=0;t<16;t++){
    const int m0 = t<<6, cur = t&1;
    if (t<15){
      const int m1 = m0+64, nxt = cur^1;
      #pragma unroll
      for (int s=0;s<2;s++){
        int idx = s*256 + T, row = idx>>3, u = idx&7, sw = (u ^ (row&7))<<3;
        glds16(Kbh + (m1+row)*64 + sw,         kls[nxt] + idx*8);
        glds16(Vbh + (long)row*1024 + m1 + sw, vls[nxt] + idx*8);
      }
    }
    const char* kb = (const char*)kls[cur];
    const char* vb = (const char*)vls[cur];
    // bias (already *log2e, bf16) as the QK^T accumulator init
    f32x4 sacc[4];
    #pragma unroll
    for (int c=0;c<4;c++){
      const int kk = m0 + 16*c + 4*g;
      const int ridx = rt - ((kk>>5)*63 + (kk&31));
      #pragma unroll
      for (int e=0;e<4;e++){
        u32 rv = rel[ridx - e];
        sacc[c][e] = __builtin_bit_cast(float, rv<<16);
      }
    }
    // QK^T (swapped): sacc[c][e] = log2e*(S+bias)[q=rowbase+cl][k=m0+16c+4g+e]
    __builtin_amdgcn_s_setprio(1);
    #pragma unroll
    for (int c=0;c<4;c++){
      const int r = 16*c + cl, rs = r&7;
      const char* kr = kb + r*128;
      bf16x8 kf0 = *reinterpret_cast<const bf16x8*>(kr + ((g    ^rs)<<4));
      bf16x8 kf1 = *reinterpret_cast<const bf16x8*>(kr + (((4+g)^rs)<<4));
      sacc[c] = __builtin_amdgcn_mfma_f32_16x16x32_bf16(kf0, qf0, sacc[c],0,0,0);
      sacc[c] = __builtin_amdgcn_mfma_f32_16x16x32_bf16(kf1, qf1, sacc[c],0,0,0);
    }
    __builtin_amdgcn_s_setprio(0);
    // p = exp2(sacc) via raw v_exp_f32; lsum deferred
    float p[4][4];
    #pragma unroll
    for (int c=0;c<4;c++)
      #pragma unroll
      for (int e=0;e<4;e++)
        p[c][e] = __builtin_amdgcn_exp2f(sacc[c][e]);
    #pragma unroll
    for (int c=0;c<4;c++) lsum += (p[c][0]+p[c][1]) + (p[c][2]+p[c][3]);
    // pack P to bf16 A-fragments (sigma: j<4 -> k=4g+j ; j>=4 -> k=16+4g+(j-4))
    bf16x8 pa0, pa1;
    #pragma unroll
    for (int e=0;e<4;e++){
      pa0[e]   = (__bf16)p[0][e];  pa0[4+e] = (__bf16)p[1][e];
      pa1[e]   = (__bf16)p[2][e];  pa1[4+e] = (__bf16)p[3][e];
    }
    // PV: sigma-permuted V -> one b128 per fragment
    __builtin_amdgcn_s_setprio(1);
    #pragma unroll
    for (int ks=0;ks<2;ks++){
      const bf16x8 pa = ks ? pa1 : pa0;
      #pragma unroll
      for (int c2=0;c2<4;c2++){
        const int dd = 16*c2 + cl, dsw = dd&7;
        bf16x8 vf = *reinterpret_cast<const bf16x8*>(vb + dd*128 + (((4*ks+g)^dsw)<<4));
        oacc[c2] = __builtin_amdgcn_mfma_f32_16x16x32_bf16(pa, vf, oacc[c2],0,0,0);
      }
    }
    __builtin_amdgcn_s_setprio(0);
    __syncthreads();
  }
  // deferred l reduction across the 4 g-groups, then broadcast to O-rows
  lsum += __shfl_xor(lsum, 16, 64);
  lsum += __shfl_xor(lsum, 32, 64);
  #pragma unroll
  for (int e=0;e<4;e++){
    float inv = 1.0f/__shfl(lsum, 4*g+e, 64);
    const long orow = (long)b*1024 + rowbase + 4*g + e;
    #pragma unroll
    for (int c2=0;c2<4;c2++)
      Ao[orow*512 + h*64 + 16*c2 + cl] = f2bf(oacc[c2][e]*inv);
  }
}

extern "C" void kernel_launch(void* const* d_in, const int* in_sizes, int n_in,
                              void* d_out, int out_size, void* d_ws, size_t ws_size,
                              hipStream_t stream)
{
  const float* x         = (const float*)d_in[0];
  const float* w_qkv     = (const float*)d_in[1];
  const float* b_qkv     = (const float*)d_in[2];
  const float* w_proj    = (const float*)d_in[3];
  const float* b_proj    = (const float*)d_in[4];
  const float* rel_table = (const float*)d_in[5];
  const float* pe_w      = (const float*)d_in[6];
  (void)in_sizes; (void)n_in; (void)out_size; (void)ws_size;

  u16* ws    = (u16*)d_ws;
  u16* x_bf  = ws;                  // 8192*512 (reused for relT after gemm<0>)
  u16* wq_bf = x_bf  + 4194304;     // 1536*512
  u16* wp_bf = wq_bf + 786432;      // 512*512
  u16* q_bf  = wp_bf + 262144;      // [B,H,N,64] pre-scaled by 0.125*log2e
  u16* k_bf  = q_bf  + 4194304;     // [B,H,N,64]
  u16* vt_bf = k_bf  + 4194304;     // [B,H,64,N] sigma-permuted tokens
  u16* qp_bf = vt_bf + 4194304;     // Q' = q~ + conv(q~)
  u16* ao_bf = qp_bf + 4194304;     // attention out [B,N,C]
  u16* relT  = x_bf;                // [H][3969] bf16 (*log2e), written after gemm<0>

  k_cvt<<<4096,256,0,stream>>>(x, x_bf, 1048576);
  k_cvt<<<768,256,0,stream>>>(w_qkv, wq_bf, 196608);
  k_cvt<<<256,256,0,stream>>>(w_proj, wp_bf, 65536);
  k_gemm<0><<<dim3(12,64),256,0,stream>>>(x_bf, wq_bf, b_qkv, q_bf, k_bf, vt_bf, nullptr);
  k_rel<<<dim3(16,8),256,0,stream>>>(rel_table, relT);
  k_qconv<<<2048,256,0,stream>>>(q_bf, qp_bf, pe_w);
  k_attn<<<1024,256,0,stream>>>(qp_bf, k_bf, vt_bf, relT, ao_bf);
  k_gemm<1><<<dim3(4,64),256,0,stream>>>(ao_bf, wp_bf, b_proj, nullptr, nullptr, nullptr, (float*)d_out);
}

// Round 5
// 101.969 us; speedup vs baseline: 2.4066x; 1.1790x over previous
//
#include <hip/hip_runtime.h>

typedef __bf16 bf16x8 __attribute__((ext_vector_type(8)));
typedef float f32x4 __attribute__((ext_vector_type(4)));
typedef unsigned short u16;
typedef unsigned int u32;
typedef unsigned long long u64;

__device__ __forceinline__ float bf2f(u16 x){ u32 u = ((u32)x)<<16; return __builtin_bit_cast(float,u); }
__device__ __forceinline__ u16 f2bf(float f){ u32 u = __builtin_bit_cast(u32,f); u = (u + 0x7fffu + ((u>>16)&1u)) >> 16; return (u16)u; }

__device__ __forceinline__ void glds16(const u16* g, u16* l){
  __builtin_amdgcn_global_load_lds((const __attribute__((address_space(1))) u32*)g,
                                   (__attribute__((address_space(3))) u32*)l, 16, 0, 0);
}

static constexpr float L2E = 1.4426950408889634f;
static constexpr float QSC = 0.125f * 1.4426950408889634f;  // SCALE * log2(e)

// ---------------- f32 -> bf16 bulk convert (4 elems/thread) ----------------
__global__ void k_cvt(const float* __restrict__ s, u16* __restrict__ d, int n4){
  int i = blockIdx.x*256 + threadIdx.x;
  if (i >= n4) return;
  float4 v = reinterpret_cast<const float4*>(s)[i];
  ushort4 o = make_ushort4(f2bf(v.x), f2bf(v.y), f2bf(v.z), f2bf(v.w));
  reinterpret_cast<ushort4*>(d)[i] = o;
}

// ------- rel_table transpose + pre-scale by log2(e), bf16 out --------------
__global__ void k_rel(const float* __restrict__ rt, u16* __restrict__ o){
  int i = blockIdx.x*256 + threadIdx.x;
  int h = blockIdx.y;
  if (i < 3969) o[h*3969+i] = f2bf(rt[i*8+h] * L2E);
}

// ------- depthwise 15-tap conv along token axis on pre-scaled Q ------------
__device__ __forceinline__ void acc8(float* acc, uint4 v, float w){
  acc[0]=fmaf(w, bf2f((u16)(v.x)),     acc[0]); acc[1]=fmaf(w, bf2f((u16)(v.x>>16)), acc[1]);
  acc[2]=fmaf(w, bf2f((u16)(v.y)),     acc[2]); acc[3]=fmaf(w, bf2f((u16)(v.y>>16)), acc[3]);
  acc[4]=fmaf(w, bf2f((u16)(v.z)),     acc[4]); acc[5]=fmaf(w, bf2f((u16)(v.z>>16)), acc[5]);
  acc[6]=fmaf(w, bf2f((u16)(v.w)),     acc[6]); acc[7]=fmaf(w, bf2f((u16)(v.w>>16)), acc[7]);
}
__global__ void k_qconv(const u16* __restrict__ q, u16* __restrict__ qp, const float* __restrict__ pw){
  int idx = blockIdx.x*256 + threadIdx.x;      // 524288 = 64bh * 1024n * 8 dchunks
  int dc = idx&7, n = (idx>>3)&1023, bh = idx>>13, h = bh&7;
  const u16* base = q + (long)bh*65536 + dc*8;
  float wgt[15];
  #pragma unroll
  for (int t=0;t<15;t++) wgt[t] = pw[h*15+t];
  float acc[8];
  {
    uint4 cv = *reinterpret_cast<const uint4*>(base + n*64);
    acc[0]=bf2f((u16)cv.x); acc[1]=bf2f((u16)(cv.x>>16));
    acc[2]=bf2f((u16)cv.y); acc[3]=bf2f((u16)(cv.y>>16));
    acc[4]=bf2f((u16)cv.z); acc[5]=bf2f((u16)(cv.z>>16));
    acc[6]=bf2f((u16)cv.w); acc[7]=bf2f((u16)(cv.w>>16));
  }
  #pragma unroll
  for (int t=0;t<15;t++){
    int nn = n - 7 + t;
    if (nn >= 0 && nn < 1024){
      uint4 v = *reinterpret_cast<const uint4*>(base + nn*64);
      acc8(acc, v, wgt[t]);
    }
  }
  u16* out = qp + (long)bh*65536 + n*64 + dc*8;
  *reinterpret_cast<ushort4*>(out)   = make_ushort4(f2bf(acc[0]),f2bf(acc[1]),f2bf(acc[2]),f2bf(acc[3]));
  *reinterpret_cast<ushort4*>(out+4) = make_ushort4(f2bf(acc[4]),f2bf(acc[5]),f2bf(acc[6]),f2bf(acc[7]));
}

// ---------------- 128x128 tile bf16 MFMA GEMM, C = A * Bw^T + bias ---------
// XCD-aware block swizzle. MODE 0: qkv scatter. MODE 1: f32 out.
template<int MODE>
__global__ __launch_bounds__(256) void k_gemm(
  const u16* __restrict__ A, const u16* __restrict__ Bw, const float* __restrict__ bias,
  u16* __restrict__ qo, u16* __restrict__ ko, u16* __restrict__ vo, float* __restrict__ co)
{
  constexpr int K = 512;
  constexpr int NX = (MODE==0) ? 12 : 4;
  constexpr int CPX = NX*64/8;
  __shared__ __align__(16) u16 lA[128*32];
  __shared__ __align__(16) u16 lB[128*32];
  const int lin = blockIdx.y*NX + blockIdx.x;
  const int swz = (lin&7)*CPX + (lin>>3);
  const int i0 = (swz/NX)*128, j0 = (swz%NX)*128;
  const int T = threadIdx.x;
  const int w = T>>6, lane = T&63, g = lane>>4, cl = lane&15;
  const int wr = (w>>1)*64, wc = (w&1)*64;
  const int sr = T>>2, sk = 8*(T&3);
  f32x4 acc[4][4];
  #pragma unroll
  for (int a=0;a<4;a++)
    #pragma unroll
    for (int b=0;b<4;b++) acc[a][b] = (f32x4){0.f,0.f,0.f,0.f};

  for (int k0=0;k0<K;k0+=32){
    __syncthreads();
    glds16(A  + (long)(i0+sr)*K    + k0 + sk, lA + 8*T);
    glds16(A  + (long)(i0+64+sr)*K + k0 + sk, lA + 2048 + 8*T);
    glds16(Bw + (long)(j0+sr)*K    + k0 + sk, lB + 8*T);
    glds16(Bw + (long)(j0+64+sr)*K + k0 + sk, lB + 2048 + 8*T);
    __syncthreads();
    bf16x8 af[4], bfr[4];
    #pragma unroll
    for (int mf=0;mf<4;mf++) af[mf]  = *reinterpret_cast<const bf16x8*>(lA + (wr+16*mf+cl)*32 + 8*g);
    #pragma unroll
    for (int nf=0;nf<4;nf++) bfr[nf] = *reinterpret_cast<const bf16x8*>(lB + (wc+16*nf+cl)*32 + 8*g);
    #pragma unroll
    for (int mf=0;mf<4;mf++)
      #pragma unroll
      for (int nf=0;nf<4;nf++)
        acc[mf][nf] = __builtin_amdgcn_mfma_f32_16x16x32_bf16(af[mf], bfr[nf], acc[mf][nf], 0,0,0);
  }

  #pragma unroll
  for (int mf=0;mf<4;mf++){
    #pragma unroll
    for (int nf=0;nf<4;nf++){
      const int col = j0 + wc + 16*nf + cl;
      const float bb = bias[col];
      const int row0 = i0 + wr + 16*mf + 4*g;
      if (MODE==0){
        const int part = col>>9, h=(col>>6)&7, dd=col&63;
        const int b = row0>>10, n0 = row0&1023, bh = b*8+h;
        if (part==2){
          // V^T sigma-permuted within 32-token blocks
          const int a32 = n0 & ~31, G = (n0>>2)&7;
          const int stb = ((G&3)<<3) | ((G>>2)<<2);
          ushort4 pk = make_ushort4(f2bf(acc[mf][nf][0]+bb), f2bf(acc[mf][nf][1]+bb),
                                    f2bf(acc[mf][nf][2]+bb), f2bf(acc[mf][nf][3]+bb));
          *reinterpret_cast<ushort4*>(vo + ((long)bh*64+dd)*1024 + a32 + stb) = pk;
        } else {
          #pragma unroll
          for (int e=0;e<4;e++){
            float v = acc[mf][nf][e] + bb;
            if (part==0) qo[((long)bh*1024+n0+e)*64+dd] = f2bf(v*QSC);
            else         ko[((long)bh*1024+n0+e)*64+dd] = f2bf(v);
          }
        }
      } else {
        #pragma unroll
        for (int e=0;e<4;e++)
          co[(long)(row0+e)*512 + col] = acc[mf][nf][e] + bb;
      }
    }
  }
}

// ---------------- fused window attention, v5 -------------------------------
// Counted-vmcnt 2-barrier pipeline (no vmcnt(0) drain in loop), rel bias from
// global (VMEM pipe), LDS = K/V dbuf only (32 KB). P in regs, no-max softmax.
__global__ __launch_bounds__(256,4) void k_attn(
  const u16* __restrict__ Qp, const u16* __restrict__ Kb, const u16* __restrict__ VT,
  const u16* __restrict__ relT, u16* __restrict__ Ao)
{
  __shared__ __align__(16) u16 kls[2][4096];
  __shared__ __align__(16) u16 vls[2][4096];
  const int bid = blockIdx.x;
  const int xcd = bid&7, slot = bid>>3;
  const int bh = xcd*8 + (slot>>4), rb = slot&15;
  const int b = bh>>3, h = bh&7;
  const int T = threadIdx.x, w=T>>6, lane=T&63, g=lane>>4, cl=lane&15;
  const int rowbase = rb*64 + w*16;
  const int qrow = rowbase + cl;
  const u16* Qr = Qp + ((long)bh*1024 + qrow)*64;
  const bf16x8 qf0 = *reinterpret_cast<const bf16x8*>(Qr + 8*g);
  const bf16x8 qf1 = *reinterpret_cast<const bf16x8*>(Qr + 32 + 8*g);
  const int rt = (qrow>>5)*63 + (qrow&31) + 1984;
  const u16* relTh = relT + h*3969;
  const u16* Kbh = Kb + (long)bh*65536;
  const u16* Vbh = VT + (long)bh*65536;
  float lsum = 0.f;
  f32x4 oacc[4];
  #pragma unroll
  for (int c=0;c<4;c++) oacc[c] = (f32x4){0.f,0.f,0.f,0.f};

  // prologue: stage tile 0
  #pragma unroll
  for (int s=0;s<2;s++){
    int idx = s*256 + T, row = idx>>3, u = idx&7, sw = (u ^ (row&7))<<3;
    glds16(Kbh + row*64 + sw,           kls[0] + idx*8);
    glds16(Vbh + (long)row*1024 + sw,   vls[0] + idx*8);
  }

  for (int t=0;t<16;t++){
    const int m0 = t<<6, cur = t&1;
    // rel bias loads for this tile (16 x u16, global/L2; consumed in softmax)
    u16 rv[4][4];
    #pragma unroll
    for (int c=0;c<4;c++){
      const int kk = m0 + 16*c + 4*g;
      const int ridx = rt - ((kk>>5)*63 + (kk&31));
      #pragma unroll
      for (int e=0;e<4;e++) rv[c][e] = relTh[ridx - e];
    }
    // stage next tile
    if (t<15){
      const int m1 = m0+64, nxt = cur^1;
      #pragma unroll
      for (int s=0;s<2;s++){
        int idx = s*256 + T, row = idx>>3, u = idx&7, sw = (u ^ (row&7))<<3;
        glds16(Kbh + (m1+row)*64 + sw,         kls[nxt] + idx*8);
        glds16(Vbh + (long)row*1024 + m1 + sw, vls[nxt] + idx*8);
      }
      // outstanding: stage(t)=4 (oldest) + rel=16 + stage(t+1)=4 -> keep 20
      asm volatile("s_waitcnt vmcnt(20)" ::: "memory");
    } else {
      // outstanding: stage(15)=4 (oldest) + rel=16 -> keep 16
      asm volatile("s_waitcnt vmcnt(16)" ::: "memory");
    }
    __builtin_amdgcn_s_barrier();     // buf[cur] fully written by all waves

    const char* kb = (const char*)kls[cur];
    const char* vb = (const char*)vls[cur];
    f32x4 sacc[4];
    #pragma unroll
    for (int c=0;c<4;c++) sacc[c] = (f32x4){0.f,0.f,0.f,0.f};
    __builtin_amdgcn_s_setprio(1);
    #pragma unroll
    for (int c=0;c<4;c++){
      const int r = 16*c + cl, rs = r&7;
      const char* kr = kb + r*128;
      bf16x8 kf0 = *reinterpret_cast<const bf16x8*>(kr + ((g    ^rs)<<4));
      bf16x8 kf1 = *reinterpret_cast<const bf16x8*>(kr + (((4+g)^rs)<<4));
      sacc[c] = __builtin_amdgcn_mfma_f32_16x16x32_bf16(kf0, qf0, sacc[c],0,0,0);
      sacc[c] = __builtin_amdgcn_mfma_f32_16x16x32_bf16(kf1, qf1, sacc[c],0,0,0);
    }
    __builtin_amdgcn_s_setprio(0);
    // p = exp2(s + bias); no max subtraction; lsum deferred
    float p[4][4];
    #pragma unroll
    for (int c=0;c<4;c++)
      #pragma unroll
      for (int e=0;e<4;e++){
        float bias = __builtin_bit_cast(float, ((u32)rv[c][e])<<16);
        p[c][e] = __builtin_amdgcn_exp2f(sacc[c][e] + bias);
      }
    #pragma unroll
    for (int c=0;c<4;c++) lsum += (p[c][0]+p[c][1]) + (p[c][2]+p[c][3]);
    bf16x8 pa0, pa1;
    #pragma unroll
    for (int e=0;e<4;e++){
      pa0[e]   = (__bf16)p[0][e];  pa0[4+e] = (__bf16)p[1][e];
      pa1[e]   = (__bf16)p[2][e];  pa1[4+e] = (__bf16)p[3][e];
    }
    __builtin_amdgcn_s_setprio(1);
    #pragma unroll
    for (int ks=0;ks<2;ks++){
      const bf16x8 pa = ks ? pa1 : pa0;
      #pragma unroll
      for (int c2=0;c2<4;c2++){
        const int dd = 16*c2 + cl, dsw = dd&7;
        bf16x8 vf = *reinterpret_cast<const bf16x8*>(vb + dd*128 + (((4*ks+g)^dsw)<<4));
        oacc[c2] = __builtin_amdgcn_mfma_f32_16x16x32_bf16(pa, vf, oacc[c2],0,0,0);
      }
    }
    __builtin_amdgcn_s_setprio(0);
    __builtin_amdgcn_s_barrier();     // all waves done reading buf[cur]
    asm volatile("" ::: "memory");
  }
  lsum += __shfl_xor(lsum, 16, 64);
  lsum += __shfl_xor(lsum, 32, 64);
  #pragma unroll
  for (int e=0;e<4;e++){
    float inv = 1.0f/__shfl(lsum, 4*g+e, 64);
    const long orow = (long)b*1024 + rowbase + 4*g + e;
    #pragma unroll
    for (int c2=0;c2<4;c2++)
      Ao[orow*512 + h*64 + 16*c2 + cl] = f2bf(oacc[c2][e]*inv);
  }
}

extern "C" void kernel_launch(void* const* d_in, const int* in_sizes, int n_in,
                              void* d_out, int out_size, void* d_ws, size_t ws_size,
                              hipStream_t stream)
{
  const float* x         = (const float*)d_in[0];
  const float* w_qkv     = (const float*)d_in[1];
  const float* b_qkv     = (const float*)d_in[2];
  const float* w_proj    = (const float*)d_in[3];
  const float* b_proj    = (const float*)d_in[4];
  const float* rel_table = (const float*)d_in[5];
  const float* pe_w      = (const float*)d_in[6];
  (void)in_sizes; (void)n_in; (void)out_size; (void)ws_size;

  u16* ws    = (u16*)d_ws;
  u16* x_bf  = ws;                  // 8192*512 (reused for relT after gemm<0>)
  u16* wq_bf = x_bf  + 4194304;     // 1536*512
  u16* wp_bf = wq_bf + 786432;      // 512*512
  u16* q_bf  = wp_bf + 262144;      // [B,H,N,64] pre-scaled by 0.125*log2e
  u16* k_bf  = q_bf  + 4194304;     // [B,H,N,64]
  u16* vt_bf = k_bf  + 4194304;     // [B,H,64,N] sigma-permuted tokens
  u16* qp_bf = vt_bf + 4194304;     // Q' = q~ + conv(q~)
  u16* ao_bf = qp_bf + 4194304;     // attention out [B,N,C]
  u16* relT  = x_bf;                // [H][3969] bf16 (*log2e), written after gemm<0>

  k_cvt<<<4096,256,0,stream>>>(x, x_bf, 1048576);
  k_cvt<<<768,256,0,stream>>>(w_qkv, wq_bf, 196608);
  k_cvt<<<256,256,0,stream>>>(w_proj, wp_bf, 65536);
  k_gemm<0><<<dim3(12,64),256,0,stream>>>(x_bf, wq_bf, b_qkv, q_bf, k_bf, vt_bf, nullptr);
  k_rel<<<dim3(16,8),256,0,stream>>>(rel_table, relT);
  k_qconv<<<2048,256,0,stream>>>(q_bf, qp_bf, pe_w);
  k_attn<<<1024,256,0,stream>>>(qp_bf, k_bf, vt_bf, relT, ao_bf);
  k_gemm<1><<<dim3(4,64),256,0,stream>>>(ao_bf, wp_bf, b_proj, nullptr, nullptr, nullptr, (float*)d_out);
}

// Round 6
// 85.805 us; speedup vs baseline: 2.8599x; 1.1884x over previous
//
#include <hip/hip_runtime.h>

typedef __bf16 bf16x8 __attribute__((ext_vector_type(8)));
typedef float f32x4 __attribute__((ext_vector_type(4)));
typedef unsigned short u16;
typedef unsigned int u32;
typedef unsigned long long u64;

__device__ __forceinline__ float bf2f(u16 x){ u32 u = ((u32)x)<<16; return __builtin_bit_cast(float,u); }
__device__ __forceinline__ u16 f2bf(float f){ u32 u = __builtin_bit_cast(u32,f); u = (u + 0x7fffu + ((u>>16)&1u)) >> 16; return (u16)u; }

__device__ __forceinline__ void glds16(const u16* g, u16* l){
  __builtin_amdgcn_global_load_lds((const __attribute__((address_space(1))) u32*)g,
                                   (__attribute__((address_space(3))) u32*)l, 16, 0, 0);
}

static constexpr float L2E = 1.4426950408889634f;
static constexpr float QSC = 0.125f * 1.4426950408889634f;  // SCALE * log2(e)

// ------- merged f32->bf16 converts (x, w_qkv, w_proj) + rel transpose ------
__global__ void k_cvtall(const float* __restrict__ x, const float* __restrict__ wq,
                         const float* __restrict__ wp, const float* __restrict__ rt,
                         u16* __restrict__ xo, u16* __restrict__ wqo,
                         u16* __restrict__ wpo, u16* __restrict__ relo){
  int bid = blockIdx.x;
  if (bid < 5120){
    int i = bid*256 + threadIdx.x;       // float4 index over 1310720 total
    const float* s; u16* d; int base;
    if (i < 1048576){ s=x; d=xo; base=0; }
    else if (i < 1245184){ s=wq; d=wqo; base=1048576; }
    else { s=wp; d=wpo; base=1245184; }
    int j = i - base;
    float4 v = reinterpret_cast<const float4*>(s)[j];
    reinterpret_cast<ushort4*>(d)[j] = make_ushort4(f2bf(v.x),f2bf(v.y),f2bf(v.z),f2bf(v.w));
  } else {
    int i = (bid-5120)*256 + threadIdx.x;
    if (i < 31752){
      int h = i / 3969, i2 = i - h*3969;
      relo[i] = f2bf(rt[i2*8+h]*L2E);    // relT[h][i2], pre-scaled by log2(e)
    }
  }
}

// ------- depthwise 15-tap conv along token axis on pre-scaled Q ------------
__device__ __forceinline__ void acc8(float* acc, uint4 v, float w){
  acc[0]=fmaf(w, bf2f((u16)(v.x)),     acc[0]); acc[1]=fmaf(w, bf2f((u16)(v.x>>16)), acc[1]);
  acc[2]=fmaf(w, bf2f((u16)(v.y)),     acc[2]); acc[3]=fmaf(w, bf2f((u16)(v.y>>16)), acc[3]);
  acc[4]=fmaf(w, bf2f((u16)(v.z)),     acc[4]); acc[5]=fmaf(w, bf2f((u16)(v.z>>16)), acc[5]);
  acc[6]=fmaf(w, bf2f((u16)(v.w)),     acc[6]); acc[7]=fmaf(w, bf2f((u16)(v.w>>16)), acc[7]);
}
__global__ void k_qconv(const u16* __restrict__ q, u16* __restrict__ qp, const float* __restrict__ pw){
  int idx = blockIdx.x*256 + threadIdx.x;      // 524288 = 64bh * 1024n * 8 dchunks
  int dc = idx&7, n = (idx>>3)&1023, bh = idx>>13, h = bh&7;
  const u16* base = q + (long)bh*65536 + dc*8;
  float wgt[15];
  #pragma unroll
  for (int t=0;t<15;t++) wgt[t] = pw[h*15+t];
  float acc[8];
  {
    uint4 cv = *reinterpret_cast<const uint4*>(base + n*64);
    acc[0]=bf2f((u16)cv.x); acc[1]=bf2f((u16)(cv.x>>16));
    acc[2]=bf2f((u16)cv.y); acc[3]=bf2f((u16)(cv.y>>16));
    acc[4]=bf2f((u16)cv.z); acc[5]=bf2f((u16)(cv.z>>16));
    acc[6]=bf2f((u16)cv.w); acc[7]=bf2f((u16)(cv.w>>16));
  }
  #pragma unroll
  for (int t=0;t<15;t++){
    int nn = n - 7 + t;
    if (nn >= 0 && nn < 1024){
      uint4 v = *reinterpret_cast<const uint4*>(base + nn*64);
      acc8(acc, v, wgt[t]);
    }
  }
  u16* out = qp + (long)bh*65536 + n*64 + dc*8;
  *reinterpret_cast<ushort4*>(out)   = make_ushort4(f2bf(acc[0]),f2bf(acc[1]),f2bf(acc[2]),f2bf(acc[3]));
  *reinterpret_cast<ushort4*>(out+4) = make_ushort4(f2bf(acc[4]),f2bf(acc[5]),f2bf(acc[6]),f2bf(acc[7]));
}

// ---------------- 128x128 tile bf16 MFMA GEMM, C = A * Bw^T + bias ---------
// Triple-buffered LDS, 2-ahead prefetch, counted vmcnt (no drain in loop).
// XCD-aware block swizzle. MODE 0: qkv scatter. MODE 1: f32 out.
template<int MODE>
__global__ __launch_bounds__(256) void k_gemm(
  const u16* __restrict__ A, const u16* __restrict__ Bw, const float* __restrict__ bias,
  u16* __restrict__ qo, u16* __restrict__ ko, u16* __restrict__ vo, float* __restrict__ co)
{
  constexpr int K = 512;
  constexpr int NX = (MODE==0) ? 12 : 4;
  constexpr int CPX = NX*64/8;
  __shared__ __align__(16) u16 lA[3][4096];
  __shared__ __align__(16) u16 lB[3][4096];
  const int lin = blockIdx.y*NX + blockIdx.x;
  const int swz = (lin&7)*CPX + (lin>>3);
  const int i0 = (swz/NX)*128, j0 = (swz%NX)*128;
  const int T = threadIdx.x;
  const int w = T>>6, lane = T&63, g = lane>>4, cl = lane&15;
  const int wr = (w>>1)*64, wc = (w&1)*64;
  const int sr = T>>2, sk = 8*(T&3);
  f32x4 acc[4][4];
  #pragma unroll
  for (int a=0;a<4;a++)
    #pragma unroll
    for (int b=0;b<4;b++) acc[a][b] = (f32x4){0.f,0.f,0.f,0.f};

  auto STAGE = [&](int t, u16* bA, u16* bB){
    glds16(A  + (long)(i0+sr)*K    + t*32 + sk, bA + 8*T);
    glds16(A  + (long)(i0+64+sr)*K + t*32 + sk, bA + 2048 + 8*T);
    glds16(Bw + (long)(j0+sr)*K    + t*32 + sk, bB + 8*T);
    glds16(Bw + (long)(j0+64+sr)*K + t*32 + sk, bB + 2048 + 8*T);
  };
  STAGE(0, lA[0], lB[0]);
  STAGE(1, lA[1], lB[1]);
  int cur = 0, sb = 2;
  for (int t=0;t<16;t++){
    if (t<14){
      STAGE(t+2, lA[sb], lB[sb]);
      asm volatile("s_waitcnt vmcnt(8)" ::: "memory");
    } else if (t==14){
      asm volatile("s_waitcnt vmcnt(4)" ::: "memory");
    } else {
      asm volatile("s_waitcnt vmcnt(0)" ::: "memory");
    }
    __builtin_amdgcn_s_barrier();
    const u16* cA = lA[cur];
    const u16* cB = lB[cur];
    bf16x8 af[4], bfr[4];
    #pragma unroll
    for (int mf=0;mf<4;mf++) af[mf]  = *reinterpret_cast<const bf16x8*>(cA + (wr+16*mf+cl)*32 + 8*g);
    #pragma unroll
    for (int nf=0;nf<4;nf++) bfr[nf] = *reinterpret_cast<const bf16x8*>(cB + (wc+16*nf+cl)*32 + 8*g);
    __builtin_amdgcn_s_setprio(1);
    #pragma unroll
    for (int mf=0;mf<4;mf++)
      #pragma unroll
      for (int nf=0;nf<4;nf++)
        acc[mf][nf] = __builtin_amdgcn_mfma_f32_16x16x32_bf16(af[mf], bfr[nf], acc[mf][nf], 0,0,0);
    __builtin_amdgcn_s_setprio(0);
    __builtin_amdgcn_s_barrier();
    asm volatile("" ::: "memory");
    cur = (cur==2)?0:cur+1;
    sb  = (sb==2)?0:sb+1;
  }

  #pragma unroll
  for (int mf=0;mf<4;mf++){
    #pragma unroll
    for (int nf=0;nf<4;nf++){
      const int col = j0 + wc + 16*nf + cl;
      const float bb = bias[col];
      const int row0 = i0 + wr + 16*mf + 4*g;
      if (MODE==0){
        const int part = col>>9, h=(col>>6)&7, dd=col&63;
        const int b = row0>>10, n0 = row0&1023, bh = b*8+h;
        if (part==2){
          // V^T sigma-permuted within 32-token blocks
          const int a32 = n0 & ~31, G = (n0>>2)&7;
          const int stb = ((G&3)<<3) | ((G>>2)<<2);
          ushort4 pk = make_ushort4(f2bf(acc[mf][nf][0]+bb), f2bf(acc[mf][nf][1]+bb),
                                    f2bf(acc[mf][nf][2]+bb), f2bf(acc[mf][nf][3]+bb));
          *reinterpret_cast<ushort4*>(vo + ((long)bh*64+dd)*1024 + a32 + stb) = pk;
        } else {
          #pragma unroll
          for (int e=0;e<4;e++){
            float v = acc[mf][nf][e] + bb;
            if (part==0) qo[((long)bh*1024+n0+e)*64+dd] = f2bf(v*QSC);
            else         ko[((long)bh*1024+n0+e)*64+dd] = f2bf(v);
          }
        }
      } else {
        #pragma unroll
        for (int e=0;e<4;e++)
          co[(long)(row0+e)*512 + col] = acc[mf][nf][e] + bb;
      }
    }
  }
}

// ---------------- fused window attention, v6 -------------------------------
// 32 q-rows/wave (K/V fragment reads amortized 2x), triple-buffered K/V LDS,
// 2-ahead prefetch with counted vmcnt, rel bias from global, no-max softmax.
// 512 blocks x 4 waves; 128 q-rows/block.
__global__ __launch_bounds__(256,2) void k_attn(
  const u16* __restrict__ Qp, const u16* __restrict__ Kb, const u16* __restrict__ VT,
  const u16* __restrict__ relT, u16* __restrict__ Ao)
{
  __shared__ __align__(16) u16 kls[3][4096];
  __shared__ __align__(16) u16 vls[3][4096];
  const int bid = blockIdx.x;
  const int xcd = bid&7, slot = bid>>3;
  const int bh = xcd*8 + (slot>>3), rb = slot&7;  // all 8 rowblocks of a bh on one XCD
  const int b = bh>>3, h = bh&7;
  const int T = threadIdx.x, w=T>>6, lane=T&63, g=lane>>4, cl=lane&15;
  const int rowbase = rb*128 + w*32;
  const int qr[2] = { rowbase + cl, rowbase + 16 + cl };
  bf16x8 qf[2][2];
  #pragma unroll
  for (int G=0;G<2;G++){
    const u16* Qr = Qp + ((long)bh*1024 + qr[G])*64;
    qf[G][0] = *reinterpret_cast<const bf16x8*>(Qr + 8*g);
    qf[G][1] = *reinterpret_cast<const bf16x8*>(Qr + 32 + 8*g);
  }
  const int rt[2] = { (qr[0]>>5)*63 + (qr[0]&31) + 1984,
                      (qr[1]>>5)*63 + (qr[1]&31) + 1984 };
  const u16* relTh = relT + h*3969;
  const u16* Kbh = Kb + (long)bh*65536;
  const u16* Vbh = VT + (long)bh*65536;
  float lsum[2] = {0.f, 0.f};
  f32x4 oacc[2][4];
  #pragma unroll
  for (int G=0;G<2;G++)
    #pragma unroll
    for (int c=0;c<4;c++) oacc[G][c] = (f32x4){0.f,0.f,0.f,0.f};

  auto STAGE = [&](int m0, u16* kbuf, u16* vbuf){
    #pragma unroll
    for (int s=0;s<2;s++){
      int idx = s*256 + T, row = idx>>3, u = idx&7, sw = (u ^ (row&7))<<3;
      glds16(Kbh + (m0+row)*64 + sw,         kbuf + idx*8);
      glds16(Vbh + (long)row*1024 + m0 + sw, vbuf + idx*8);
    }
  };
  STAGE(0,  kls[0], vls[0]);
  STAGE(64, kls[1], vls[1]);

  int cur = 0, sb = 2;
  for (int t=0;t<16;t++){
    const int m0 = t<<6;
    // rel bias loads (32 x u16, global/L2, VMEM pipe)
    u16 rv[2][4][4];
    #pragma unroll
    for (int G=0;G<2;G++)
      #pragma unroll
      for (int c=0;c<4;c++){
        const int kk = m0 + 16*c + 4*g;
        const int ridx = rt[G] - ((kk>>5)*63 + (kk&31));
        #pragma unroll
        for (int e=0;e<4;e++) rv[G][c][e] = relTh[ridx - e];
      }
    asm volatile("" ::: "memory");   // pin rel loads before stage loads
    if (t<14){
      STAGE(m0+128, kls[sb], vls[sb]);
      // keep rel(t)=32 + stage(t+1)=4 + stage(t+2)=4 in flight
      asm volatile("s_waitcnt vmcnt(40)" ::: "memory");
    } else if (t==14){
      asm volatile("s_waitcnt vmcnt(36)" ::: "memory");
    } else {
      asm volatile("s_waitcnt vmcnt(32)" ::: "memory");
    }
    __builtin_amdgcn_s_barrier();    // K/V tile t ready

    const char* kb = (const char*)kls[cur];
    const char* vb = (const char*)vls[cur];
    f32x4 sacc[2][4];
    #pragma unroll
    for (int G=0;G<2;G++)
      #pragma unroll
      for (int c=0;c<4;c++) sacc[G][c] = (f32x4){0.f,0.f,0.f,0.f};
    __builtin_amdgcn_s_setprio(1);
    #pragma unroll
    for (int c=0;c<4;c++){
      const int r = 16*c + cl, rs = r&7;
      const char* kr = kb + r*128;
      bf16x8 kf0 = *reinterpret_cast<const bf16x8*>(kr + ((g    ^rs)<<4));
      bf16x8 kf1 = *reinterpret_cast<const bf16x8*>(kr + (((4+g)^rs)<<4));
      #pragma unroll
      for (int G=0;G<2;G++){
        sacc[G][c] = __builtin_amdgcn_mfma_f32_16x16x32_bf16(kf0, qf[G][0], sacc[G][c],0,0,0);
        sacc[G][c] = __builtin_amdgcn_mfma_f32_16x16x32_bf16(kf1, qf[G][1], sacc[G][c],0,0,0);
      }
    }
    __builtin_amdgcn_s_setprio(0);
    // p = exp2(s + bias); no max subtraction; lsum deferred
    float p[2][4][4];
    #pragma unroll
    for (int G=0;G<2;G++)
      #pragma unroll
      for (int c=0;c<4;c++)
        #pragma unroll
        for (int e=0;e<4;e++){
          float bias = __builtin_bit_cast(float, ((u32)rv[G][c][e])<<16);
          p[G][c][e] = __builtin_amdgcn_exp2f(sacc[G][c][e] + bias);
        }
    #pragma unroll
    for (int G=0;G<2;G++)
      #pragma unroll
      for (int c=0;c<4;c++) lsum[G] += (p[G][c][0]+p[G][c][1]) + (p[G][c][2]+p[G][c][3]);
    bf16x8 pa[2][2];
    #pragma unroll
    for (int G=0;G<2;G++)
      #pragma unroll
      for (int e=0;e<4;e++){
        pa[G][0][e]   = (__bf16)p[G][0][e];  pa[G][0][4+e] = (__bf16)p[G][1][e];
        pa[G][1][e]   = (__bf16)p[G][2][e];  pa[G][1][4+e] = (__bf16)p[G][3][e];
      }
    __builtin_amdgcn_s_setprio(1);
    #pragma unroll
    for (int ks=0;ks<2;ks++)
      #pragma unroll
      for (int c2=0;c2<4;c2++){
        const int dd = 16*c2 + cl, dsw = dd&7;
        bf16x8 vf = *reinterpret_cast<const bf16x8*>(vb + dd*128 + (((4*ks+g)^dsw)<<4));
        #pragma unroll
        for (int G=0;G<2;G++)
          oacc[G][c2] = __builtin_amdgcn_mfma_f32_16x16x32_bf16(pa[G][ks], vf, oacc[G][c2],0,0,0);
      }
    __builtin_amdgcn_s_setprio(0);
    __builtin_amdgcn_s_barrier();    // all waves done reading tile t buffers
    asm volatile("" ::: "memory");
    cur = (cur==2)?0:cur+1;
    sb  = (sb==2)?0:sb+1;
  }
  #pragma unroll
  for (int G=0;G<2;G++){
    lsum[G] += __shfl_xor(lsum[G], 16, 64);
    lsum[G] += __shfl_xor(lsum[G], 32, 64);
  }
  #pragma unroll
  for (int G=0;G<2;G++)
    #pragma unroll
    for (int e=0;e<4;e++){
      float inv = 1.0f/__shfl(lsum[G], 4*g+e, 64);
      const long orow = (long)b*1024 + rowbase + 16*G + 4*g + e;
      #pragma unroll
      for (int c2=0;c2<4;c2++)
        Ao[orow*512 + h*64 + 16*c2 + cl] = f2bf(oacc[G][c2][e]*inv);
    }
}

extern "C" void kernel_launch(void* const* d_in, const int* in_sizes, int n_in,
                              void* d_out, int out_size, void* d_ws, size_t ws_size,
                              hipStream_t stream)
{
  const float* x         = (const float*)d_in[0];
  const float* w_qkv     = (const float*)d_in[1];
  const float* b_qkv     = (const float*)d_in[2];
  const float* w_proj    = (const float*)d_in[3];
  const float* b_proj    = (const float*)d_in[4];
  const float* rel_table = (const float*)d_in[5];
  const float* pe_w      = (const float*)d_in[6];
  (void)in_sizes; (void)n_in; (void)out_size; (void)ws_size;

  u16* ws    = (u16*)d_ws;
  u16* x_bf  = ws;                  // 8192*512
  u16* wq_bf = x_bf  + 4194304;     // 1536*512
  u16* wp_bf = wq_bf + 786432;      // 512*512
  u16* q_bf  = wp_bf + 262144;      // [B,H,N,64] pre-scaled by 0.125*log2e
  u16* k_bf  = q_bf  + 4194304;     // [B,H,N,64]
  u16* vt_bf = k_bf  + 4194304;     // [B,H,64,N] sigma-permuted tokens
  u16* qp_bf = vt_bf + 4194304;     // Q' = q~ + conv(q~)
  u16* ao_bf = qp_bf + 4194304;     // attention out [B,N,C]
  u16* relT  = ao_bf + 4194304;     // [H][3969] bf16 (*log2e)

  k_cvtall<<<5245,256,0,stream>>>(x, w_qkv, w_proj, rel_table, x_bf, wq_bf, wp_bf, relT);
  k_gemm<0><<<dim3(12,64),256,0,stream>>>(x_bf, wq_bf, b_qkv, q_bf, k_bf, vt_bf, nullptr);
  k_qconv<<<2048,256,0,stream>>>(q_bf, qp_bf, pe_w);
  k_attn<<<512,256,0,stream>>>(qp_bf, k_bf, vt_bf, relT, ao_bf);
  k_gemm<1><<<dim3(4,64),256,0,stream>>>(ao_bf, wp_bf, b_proj, nullptr, nullptr, nullptr, (float*)d_out);
}

// Round 7
// 84.175 us; speedup vs baseline: 2.9153x; 1.0194x over previous
//
#include <hip/hip_runtime.h>

typedef __bf16 bf16x8 __attribute__((ext_vector_type(8)));
typedef float f32x4 __attribute__((ext_vector_type(4)));
typedef unsigned short u16;
typedef unsigned int u32;
typedef unsigned long long u64;

__device__ __forceinline__ float bf2f(u16 x){ u32 u = ((u32)x)<<16; return __builtin_bit_cast(float,u); }
__device__ __forceinline__ u16 f2bf(float f){ u32 u = __builtin_bit_cast(u32,f); u = (u + 0x7fffu + ((u>>16)&1u)) >> 16; return (u16)u; }

__device__ __forceinline__ void glds16(const u16* g, u16* l){
  __builtin_amdgcn_global_load_lds((const __attribute__((address_space(1))) u32*)g,
                                   (__attribute__((address_space(3))) u32*)l, 16, 0, 0);
}

static constexpr float L2E = 1.4426950408889634f;
static constexpr float QSC = 0.125f * 1.4426950408889634f;  // SCALE * log2(e)

// --- merged f32->bf16 converts (x, w_qkv, w_proj) + packed rel table -------
// relT2[h][i] = u64 of 4 bf16 {rel[i-3],rel[i-2],rel[i-1],rel[i]} * log2(e)
__global__ void k_cvtall(const float* __restrict__ x, const float* __restrict__ wq,
                         const float* __restrict__ wp, const float* __restrict__ rt,
                         u16* __restrict__ xo, u16* __restrict__ wqo,
                         u16* __restrict__ wpo, u64* __restrict__ rel2){
  int bid = blockIdx.x;
  if (bid < 5120){
    int i = bid*256 + threadIdx.x;       // float4 index over 1310720 total
    const float* s; u16* d; int base;
    if (i < 1048576){ s=x; d=xo; base=0; }
    else if (i < 1245184){ s=wq; d=wqo; base=1048576; }
    else { s=wp; d=wpo; base=1245184; }
    int j = i - base;
    float4 v = reinterpret_cast<const float4*>(s)[j];
    reinterpret_cast<ushort4*>(d)[j] = make_ushort4(f2bf(v.x),f2bf(v.y),f2bf(v.z),f2bf(v.w));
  } else {
    int i = (bid-5120)*256 + threadIdx.x;
    if (i < 31752){
      int h = i / 3969, i2 = i - h*3969;
      u64 v = 0;
      #pragma unroll
      for (int j=0;j<4;j++){
        int idx = i2-3+j;
        u16 bb = 0;
        if (idx >= 0) bb = f2bf(rt[idx*8+h]*L2E);
        v |= (u64)bb << (16*j);
      }
      rel2[i] = v;
    }
  }
}

// ------- depthwise 15-tap conv along token axis on pre-scaled Q ------------
__device__ __forceinline__ void acc8(float* acc, uint4 v, float w){
  acc[0]=fmaf(w, bf2f((u16)(v.x)),     acc[0]); acc[1]=fmaf(w, bf2f((u16)(v.x>>16)), acc[1]);
  acc[2]=fmaf(w, bf2f((u16)(v.y)),     acc[2]); acc[3]=fmaf(w, bf2f((u16)(v.y>>16)), acc[3]);
  acc[4]=fmaf(w, bf2f((u16)(v.z)),     acc[4]); acc[5]=fmaf(w, bf2f((u16)(v.z>>16)), acc[5]);
  acc[6]=fmaf(w, bf2f((u16)(v.w)),     acc[6]); acc[7]=fmaf(w, bf2f((u16)(v.w>>16)), acc[7]);
}
__global__ void k_qconv(const u16* __restrict__ q, u16* __restrict__ qp, const float* __restrict__ pw){
  int idx = blockIdx.x*256 + threadIdx.x;      // 524288 = 64bh * 1024n * 8 dchunks
  int dc = idx&7, n = (idx>>3)&1023, bh = idx>>13, h = bh&7;
  const u16* base = q + (long)bh*65536 + dc*8;
  float wgt[15];
  #pragma unroll
  for (int t=0;t<15;t++) wgt[t] = pw[h*15+t];
  float acc[8];
  {
    uint4 cv = *reinterpret_cast<const uint4*>(base + n*64);
    acc[0]=bf2f((u16)cv.x); acc[1]=bf2f((u16)(cv.x>>16));
    acc[2]=bf2f((u16)cv.y); acc[3]=bf2f((u16)(cv.y>>16));
    acc[4]=bf2f((u16)cv.z); acc[5]=bf2f((u16)(cv.z>>16));
    acc[6]=bf2f((u16)cv.w); acc[7]=bf2f((u16)(cv.w>>16));
  }
  #pragma unroll
  for (int t=0;t<15;t++){
    int nn = n - 7 + t;
    if (nn >= 0 && nn < 1024){
      uint4 v = *reinterpret_cast<const uint4*>(base + nn*64);
      acc8(acc, v, wgt[t]);
    }
  }
  u16* out = qp + (long)bh*65536 + n*64 + dc*8;
  *reinterpret_cast<ushort4*>(out)   = make_ushort4(f2bf(acc[0]),f2bf(acc[1]),f2bf(acc[2]),f2bf(acc[3]));
  *reinterpret_cast<ushort4*>(out+4) = make_ushort4(f2bf(acc[4]),f2bf(acc[5]),f2bf(acc[6]),f2bf(acc[7]));
}

// ---------------- 128x128 tile bf16 MFMA GEMM, C = A * Bw^T + bias ---------
// Triple-buffered LDS, single barrier per k-step (stage issued post-barrier),
// counted vmcnt. XCD-aware swizzle. MODE 0: qkv scatter. MODE 1: f32 out.
template<int MODE>
__global__ __launch_bounds__(256) void k_gemm(
  const u16* __restrict__ A, const u16* __restrict__ Bw, const float* __restrict__ bias,
  u16* __restrict__ qo, u16* __restrict__ ko, u16* __restrict__ vo, float* __restrict__ co)
{
  constexpr int K = 512;
  constexpr int NX = (MODE==0) ? 12 : 4;
  constexpr int CPX = NX*64/8;
  __shared__ __align__(16) u16 lA[3][4096];
  __shared__ __align__(16) u16 lB[3][4096];
  const int lin = blockIdx.y*NX + blockIdx.x;
  const int swz = (lin&7)*CPX + (lin>>3);
  const int i0 = (swz/NX)*128, j0 = (swz%NX)*128;
  const int T = threadIdx.x;
  const int w = T>>6, lane = T&63, g = lane>>4, cl = lane&15;
  const int wr = (w>>1)*64, wc = (w&1)*64;
  const int sr = T>>2, sk = 8*(T&3);
  f32x4 acc[4][4];
  #pragma unroll
  for (int a=0;a<4;a++)
    #pragma unroll
    for (int b=0;b<4;b++) acc[a][b] = (f32x4){0.f,0.f,0.f,0.f};

  auto STAGE = [&](int t, u16* bA, u16* bB){
    glds16(A  + (long)(i0+sr)*K    + t*32 + sk, bA + 8*T);
    glds16(A  + (long)(i0+64+sr)*K + t*32 + sk, bA + 2048 + 8*T);
    glds16(Bw + (long)(j0+sr)*K    + t*32 + sk, bB + 8*T);
    glds16(Bw + (long)(j0+64+sr)*K + t*32 + sk, bB + 2048 + 8*T);
  };
  STAGE(0, lA[0], lB[0]);
  STAGE(1, lA[1], lB[1]);
  int cur = 0, sb = 2;
  for (int t=0;t<16;t++){
    if (t<15) asm volatile("s_waitcnt vmcnt(4)" ::: "memory");
    else      asm volatile("s_waitcnt vmcnt(0)" ::: "memory");
    __builtin_amdgcn_s_barrier();
    asm volatile("" ::: "memory");
    if (t<14) STAGE(t+2, lA[sb], lB[sb]);
    const u16* cA = lA[cur];
    const u16* cB = lB[cur];
    bf16x8 af[4], bfr[4];
    #pragma unroll
    for (int mf=0;mf<4;mf++) af[mf]  = *reinterpret_cast<const bf16x8*>(cA + (wr+16*mf+cl)*32 + 8*g);
    #pragma unroll
    for (int nf=0;nf<4;nf++) bfr[nf] = *reinterpret_cast<const bf16x8*>(cB + (wc+16*nf+cl)*32 + 8*g);
    __builtin_amdgcn_s_setprio(1);
    #pragma unroll
    for (int mf=0;mf<4;mf++)
      #pragma unroll
      for (int nf=0;nf<4;nf++)
        acc[mf][nf] = __builtin_amdgcn_mfma_f32_16x16x32_bf16(af[mf], bfr[nf], acc[mf][nf], 0,0,0);
    __builtin_amdgcn_s_setprio(0);
    cur = (cur==2)?0:cur+1;
    sb  = (sb==2)?0:sb+1;
  }

  #pragma unroll
  for (int mf=0;mf<4;mf++){
    #pragma unroll
    for (int nf=0;nf<4;nf++){
      const int col = j0 + wc + 16*nf + cl;
      const float bb = bias[col];
      const int row0 = i0 + wr + 16*mf + 4*g;
      if (MODE==0){
        const int part = col>>9, h=(col>>6)&7, dd=col&63;
        const int b = row0>>10, n0 = row0&1023, bh = b*8+h;
        if (part==2){
          // V^T sigma-permuted within 32-token blocks
          const int a32 = n0 & ~31, G = (n0>>2)&7;
          const int stb = ((G&3)<<3) | ((G>>2)<<2);
          ushort4 pk = make_ushort4(f2bf(acc[mf][nf][0]+bb), f2bf(acc[mf][nf][1]+bb),
                                    f2bf(acc[mf][nf][2]+bb), f2bf(acc[mf][nf][3]+bb));
          *reinterpret_cast<ushort4*>(vo + ((long)bh*64+dd)*1024 + a32 + stb) = pk;
        } else {
          #pragma unroll
          for (int e=0;e<4;e++){
            float v = acc[mf][nf][e] + bb;
            if (part==0) qo[((long)bh*1024+n0+e)*64+dd] = f2bf(v*QSC);
            else         ko[((long)bh*1024+n0+e)*64+dd] = f2bf(v);
          }
        }
      } else {
        #pragma unroll
        for (int e=0;e<4;e++)
          co[(long)(row0+e)*512 + col] = acc[mf][nf][e] + bb;
      }
    }
  }
}

// ---------------- fused window attention, v7 -------------------------------
// Quad-buffered K/V LDS, ONE barrier per tile (stage post-barrier), counted
// vmcnt, packed-u64 rel gathers, 32 q-rows/wave, no-max softmax.
__global__ __launch_bounds__(256,2) void k_attn(
  const u16* __restrict__ Qp, const u16* __restrict__ Kb, const u16* __restrict__ VT,
  const u64* __restrict__ relT2, u16* __restrict__ Ao)
{
  __shared__ __align__(16) u16 kls[4][4096];
  __shared__ __align__(16) u16 vls[4][4096];
  const int bid = blockIdx.x;
  const int xcd = bid&7, slot = bid>>3;
  const int bh = xcd*8 + (slot>>3), rb = slot&7;  // all 8 rowblocks of a bh on one XCD
  const int b = bh>>3, h = bh&7;
  const int T = threadIdx.x, w=T>>6, lane=T&63, g=lane>>4, cl=lane&15;
  const int rowbase = rb*128 + w*32;
  const int qr[2] = { rowbase + cl, rowbase + 16 + cl };
  bf16x8 qf[2][2];
  #pragma unroll
  for (int G=0;G<2;G++){
    const u16* Qr = Qp + ((long)bh*1024 + qr[G])*64;
    qf[G][0] = *reinterpret_cast<const bf16x8*>(Qr + 8*g);
    qf[G][1] = *reinterpret_cast<const bf16x8*>(Qr + 32 + 8*g);
  }
  const int rt[2] = { (qr[0]>>5)*63 + (qr[0]&31) + 1984,
                      (qr[1]>>5)*63 + (qr[1]&31) + 1984 };
  const u64* relTh = relT2 + h*3969;
  const u16* Kbh = Kb + (long)bh*65536;
  const u16* Vbh = VT + (long)bh*65536;
  float lsum[2] = {0.f, 0.f};
  f32x4 oacc[2][4];
  #pragma unroll
  for (int G=0;G<2;G++)
    #pragma unroll
    for (int c=0;c<4;c++) oacc[G][c] = (f32x4){0.f,0.f,0.f,0.f};

  auto STAGE = [&](int m0, int bi){
    #pragma unroll
    for (int s=0;s<2;s++){
      int idx = s*256 + T, row = idx>>3, u = idx&7, sw = (u ^ (row&7))<<3;
      glds16(Kbh + (m0+row)*64 + sw,         kls[bi] + idx*8);
      glds16(Vbh + (long)row*1024 + m0 + sw, vls[bi] + idx*8);
    }
  };
  STAGE(0,0); STAGE(64,1); STAGE(128,2);

  for (int t=0;t<16;t++){
    const int m0 = t<<6;
    // packed rel gathers: one u64 per (G,c) covers e=0..3 (elem j = rel[i-3+j])
    u64 rx[2][4];
    #pragma unroll
    for (int G=0;G<2;G++)
      #pragma unroll
      for (int c=0;c<4;c++){
        const int kk = m0 + 16*c + 4*g;
        rx[G][c] = relTh[rt[G] - ((kk>>5)*63 + (kk&31))];
      }
    if (t<=13)      asm volatile("s_waitcnt vmcnt(16)" ::: "memory");
    else if (t==14) asm volatile("s_waitcnt vmcnt(12)" ::: "memory");
    else            asm volatile("s_waitcnt vmcnt(8)"  ::: "memory");
    __builtin_amdgcn_s_barrier();
    asm volatile("" ::: "memory");
    if (t<13) STAGE(m0+192, (t+3)&3);

    const char* kb = (const char*)kls[t&3];
    const char* vb = (const char*)vls[t&3];
    f32x4 sacc[2][4];
    #pragma unroll
    for (int G=0;G<2;G++)
      #pragma unroll
      for (int c=0;c<4;c++) sacc[G][c] = (f32x4){0.f,0.f,0.f,0.f};
    __builtin_amdgcn_s_setprio(1);
    #pragma unroll
    for (int c=0;c<4;c++){
      const int r = 16*c + cl, rs = r&7;
      const char* kr = kb + r*128;
      bf16x8 kf0 = *reinterpret_cast<const bf16x8*>(kr + ((g    ^rs)<<4));
      bf16x8 kf1 = *reinterpret_cast<const bf16x8*>(kr + (((4+g)^rs)<<4));
      #pragma unroll
      for (int G=0;G<2;G++){
        sacc[G][c] = __builtin_amdgcn_mfma_f32_16x16x32_bf16(kf0, qf[G][0], sacc[G][c],0,0,0);
        sacc[G][c] = __builtin_amdgcn_mfma_f32_16x16x32_bf16(kf1, qf[G][1], sacc[G][c],0,0,0);
      }
    }
    __builtin_amdgcn_s_setprio(0);
    // p = exp2(s + bias); bias e = bf16 lane (3-e) of rx
    float p[2][4][4];
    #pragma unroll
    for (int G=0;G<2;G++)
      #pragma unroll
      for (int c=0;c<4;c++)
        #pragma unroll
        for (int e=0;e<4;e++){
          float bias = __builtin_bit_cast(float, ((u32)((u16)(rx[G][c] >> (16*(3-e)))))<<16);
          p[G][c][e] = __builtin_amdgcn_exp2f(sacc[G][c][e] + bias);
        }
    #pragma unroll
    for (int G=0;G<2;G++)
      #pragma unroll
      for (int c=0;c<4;c++) lsum[G] += (p[G][c][0]+p[G][c][1]) + (p[G][c][2]+p[G][c][3]);
    bf16x8 pa[2][2];
    #pragma unroll
    for (int G=0;G<2;G++)
      #pragma unroll
      for (int e=0;e<4;e++){
        pa[G][0][e]   = (__bf16)p[G][0][e];  pa[G][0][4+e] = (__bf16)p[G][1][e];
        pa[G][1][e]   = (__bf16)p[G][2][e];  pa[G][1][4+e] = (__bf16)p[G][3][e];
      }
    __builtin_amdgcn_s_setprio(1);
    #pragma unroll
    for (int ks=0;ks<2;ks++)
      #pragma unroll
      for (int c2=0;c2<4;c2++){
        const int dd = 16*c2 + cl, dsw = dd&7;
        bf16x8 vf = *reinterpret_cast<const bf16x8*>(vb + dd*128 + (((4*ks+g)^dsw)<<4));
        #pragma unroll
        for (int G=0;G<2;G++)
          oacc[G][c2] = __builtin_amdgcn_mfma_f32_16x16x32_bf16(pa[G][ks], vf, oacc[G][c2],0,0,0);
      }
    __builtin_amdgcn_s_setprio(0);
  }
  #pragma unroll
  for (int G=0;G<2;G++){
    lsum[G] += __shfl_xor(lsum[G], 16, 64);
    lsum[G] += __shfl_xor(lsum[G], 32, 64);
  }
  #pragma unroll
  for (int G=0;G<2;G++)
    #pragma unroll
    for (int e=0;e<4;e++){
      float inv = 1.0f/__shfl(lsum[G], 4*g+e, 64);
      const long orow = (long)b*1024 + rowbase + 16*G + 4*g + e;
      #pragma unroll
      for (int c2=0;c2<4;c2++)
        Ao[orow*512 + h*64 + 16*c2 + cl] = f2bf(oacc[G][c2][e]*inv);
    }
}

extern "C" void kernel_launch(void* const* d_in, const int* in_sizes, int n_in,
                              void* d_out, int out_size, void* d_ws, size_t ws_size,
                              hipStream_t stream)
{
  const float* x         = (const float*)d_in[0];
  const float* w_qkv     = (const float*)d_in[1];
  const float* b_qkv     = (const float*)d_in[2];
  const float* w_proj    = (const float*)d_in[3];
  const float* b_proj    = (const float*)d_in[4];
  const float* rel_table = (const float*)d_in[5];
  const float* pe_w      = (const float*)d_in[6];
  (void)in_sizes; (void)n_in; (void)out_size; (void)ws_size;

  u16* ws    = (u16*)d_ws;
  u16* x_bf  = ws;                  // 8192*512
  u16* wq_bf = x_bf  + 4194304;     // 1536*512
  u16* wp_bf = wq_bf + 786432;      // 512*512
  u16* q_bf  = wp_bf + 262144;      // [B,H,N,64] pre-scaled by 0.125*log2e
  u16* k_bf  = q_bf  + 4194304;     // [B,H,N,64]
  u16* vt_bf = k_bf  + 4194304;     // [B,H,64,N] sigma-permuted tokens
  u16* qp_bf = vt_bf + 4194304;     // Q' = q~ + conv(q~)
  u16* ao_bf = qp_bf + 4194304;     // attention out [B,N,C]
  u64* relT2 = (u64*)(ao_bf + 4194304);  // [H][3969] packed u64 (8B aligned)

  k_cvtall<<<5245,256,0,stream>>>(x, w_qkv, w_proj, rel_table, x_bf, wq_bf, wp_bf, relT2);
  k_gemm<0><<<dim3(12,64),256,0,stream>>>(x_bf, wq_bf, b_qkv, q_bf, k_bf, vt_bf, nullptr);
  k_qconv<<<2048,256,0,stream>>>(q_bf, qp_bf, pe_w);
  k_attn<<<512,256,0,stream>>>(qp_bf, k_bf, vt_bf, relT2, ao_bf);
  k_gemm<1><<<dim3(4,64),256,0,stream>>>(ao_bf, wp_bf, b_proj, nullptr, nullptr, nullptr, (float*)d_out);
}